// Round 1
// baseline (8215.972 us; speedup 1.0000x reference)
//
#include <hip/hip_runtime.h>
#include <math.h>

// B=2048, A=32 -> R=65536 rows. E_IN=160, H=128, HE=256, NACT=32, G=3, TAU=1.
#define R_TOTAL 65536

__device__ __forceinline__ float sigmoidf_(float x) { return 1.f / (1.f + expf(-x)); }

// ---------------- generic SGEMM: C = act(A[M,K] @ B[K,N] + bias) ----------------
// BM=BN=64, BK=16, 256 threads, 4x4 micro-tile. ACT: 0 none, 1 relu, 2 tanh.
template <int ACT>
__global__ __launch_bounds__(256) void sgemm_kernel(
    const float* __restrict__ A, const float* __restrict__ B,
    const float* __restrict__ bias, float* __restrict__ C,
    int M, int N, int K) {
  __shared__ float As[16][68];
  __shared__ float Bs[16][68];
  const int row0 = blockIdx.y * 64;
  const int col0 = blockIdx.x * 64;
  const int tid = threadIdx.x;
  const int tr = tid >> 4, tc = tid & 15;
  float acc[4][4] = {};
  for (int k0 = 0; k0 < K; k0 += 16) {
#pragma unroll
    for (int i = 0; i < 4; ++i) {
      int idx = tid + i * 256;
      int m = idx >> 4, k = idx & 15;
      As[k][m] = (k0 + k < K) ? A[(size_t)(row0 + m) * K + k0 + k] : 0.f;
    }
#pragma unroll
    for (int i = 0; i < 4; ++i) {
      int idx = tid + i * 256;
      int k = idx >> 6, n = idx & 63;
      Bs[k][n] = (k0 + k < K) ? B[(size_t)(k0 + k) * N + col0 + n] : 0.f;
    }
    __syncthreads();
#pragma unroll
    for (int k = 0; k < 16; ++k) {
      float4 a4 = *(const float4*)&As[k][tr * 4];
      float4 b4 = *(const float4*)&Bs[k][tc * 4];
      float a[4] = {a4.x, a4.y, a4.z, a4.w};
      float b[4] = {b4.x, b4.y, b4.z, b4.w};
#pragma unroll
      for (int i = 0; i < 4; ++i)
#pragma unroll
        for (int j = 0; j < 4; ++j) acc[i][j] = fmaf(a[i], b[j], acc[i][j]);
    }
    __syncthreads();
  }
#pragma unroll
  for (int i = 0; i < 4; ++i) {
    const size_t r = row0 + tr * 4 + i;
#pragma unroll
    for (int j = 0; j < 4; ++j) {
      int c = col0 + tc * 4 + j;
      float v = acc[i][j] + (bias ? bias[c] : 0.f);
      if (ACT == 1) v = fmaxf(v, 0.f);
      if (ACT == 2) v = tanhf(v);
      C[r * N + c] = v;
    }
  }
}

// ---------------- fused GRU: h = GRUCell(x1, h_in) ----------------
// Computes x@Wi and h@Wh tiles simultaneously (K=128 each), fused gate epilogue.
// Grid: (128/64, R/64). Logical N-tile = 64 j-columns; each j needs cates at
// cols {j, j+128, j+256} of both gi and gh.
__global__ __launch_bounds__(256) void gru_kernel(
    const float* __restrict__ X, const float* __restrict__ Hin,
    const float* __restrict__ Wi, const float* __restrict__ Wh,
    const float* __restrict__ bi, const float* __restrict__ bh,
    float* __restrict__ Hout) {
  __shared__ float Xs[16][68];
  __shared__ float Hs[16][68];
  __shared__ float Wis[16][196];
  __shared__ float Whs[16][196];
  const int row0 = blockIdx.y * 64;
  const int j0 = blockIdx.x * 64;
  const int tid = threadIdx.x;
  const int tr = tid >> 4, tc = tid & 15;
  float acc_r[4][4] = {}, acc_z[4][4] = {}, acc_in[4][4] = {}, acc_hn[4][4] = {};
  for (int k0 = 0; k0 < 128; k0 += 16) {
#pragma unroll
    for (int i = 0; i < 4; ++i) {
      int idx = tid + i * 256;
      int m = idx >> 4, k = idx & 15;
      Xs[k][m] = X[(size_t)(row0 + m) * 128 + k0 + k];
      Hs[k][m] = Hin[(size_t)(row0 + m) * 128 + k0 + k];
    }
#pragma unroll
    for (int i = 0; i < 12; ++i) {
      int idx = tid + i * 256;
      int k = idx / 192, c = idx % 192;
      int col = ((c >> 6) << 7) + j0 + (c & 63);  // gate*128 + j0 + jc
      Wis[k][c] = Wi[(size_t)(k0 + k) * 384 + col];
      Whs[k][c] = Wh[(size_t)(k0 + k) * 384 + col];
    }
    __syncthreads();
#pragma unroll
    for (int k = 0; k < 16; ++k) {
      float4 xa = *(const float4*)&Xs[k][tr * 4];
      float4 ha = *(const float4*)&Hs[k][tr * 4];
      float x[4] = {xa.x, xa.y, xa.z, xa.w};
      float hh[4] = {ha.x, ha.y, ha.z, ha.w};
      float4 v;
      v = *(const float4*)&Wis[k][tc * 4];
      float wri[4] = {v.x, v.y, v.z, v.w};
      v = *(const float4*)&Wis[k][64 + tc * 4];
      float wzi[4] = {v.x, v.y, v.z, v.w};
      v = *(const float4*)&Wis[k][128 + tc * 4];
      float wni[4] = {v.x, v.y, v.z, v.w};
      v = *(const float4*)&Whs[k][tc * 4];
      float wrh[4] = {v.x, v.y, v.z, v.w};
      v = *(const float4*)&Whs[k][64 + tc * 4];
      float wzh[4] = {v.x, v.y, v.z, v.w};
      v = *(const float4*)&Whs[k][128 + tc * 4];
      float wnh[4] = {v.x, v.y, v.z, v.w};
#pragma unroll
      for (int i = 0; i < 4; ++i)
#pragma unroll
        for (int j = 0; j < 4; ++j) {
          acc_r[i][j] = fmaf(x[i], wri[j], fmaf(hh[i], wrh[j], acc_r[i][j]));
          acc_z[i][j] = fmaf(x[i], wzi[j], fmaf(hh[i], wzh[j], acc_z[i][j]));
          acc_in[i][j] = fmaf(x[i], wni[j], acc_in[i][j]);
          acc_hn[i][j] = fmaf(hh[i], wnh[j], acc_hn[i][j]);
        }
    }
    __syncthreads();
  }
#pragma unroll
  for (int i = 0; i < 4; ++i) {
    const size_t r = row0 + tr * 4 + i;
    float4 hin4 = *(const float4*)&Hin[r * 128 + j0 + tc * 4];
    float hinv[4] = {hin4.x, hin4.y, hin4.z, hin4.w};
    float o[4];
#pragma unroll
    for (int j = 0; j < 4; ++j) {
      int col = j0 + tc * 4 + j;
      float rg = sigmoidf_(acc_r[i][j] + bi[col] + bh[col]);
      float zg = sigmoidf_(acc_z[i][j] + bi[128 + col] + bh[128 + col]);
      float ng = tanhf(acc_in[i][j] + bi[256 + col] + rg * (acc_hn[i][j] + bh[256 + col]));
      o[j] = (1.f - zg) * ng + zg * hinv[j];
    }
    *(float4*)&Hout[r * 128 + j0 + tc * 4] = make_float4(o[0], o[1], o[2], o[3]);
  }
}

// ---------------- attention block (one b per block) ----------------
__global__ __launch_bounds__(256) void attn_kernel(
    const float* __restrict__ Qp, const float* __restrict__ Kp,
    float* __restrict__ attn_out, float* __restrict__ si) {
  __shared__ float qs[32][129];
  __shared__ float ks[32][129];
  __shared__ float p[32][33];
  __shared__ float a2[32][33];
  const int b = blockIdx.x;
  const int tid = threadIdx.x;
  const float* qb = Qp + (size_t)b * 4096;
  const float* kb = Kp + (size_t)b * 4096;
  for (int i = tid; i < 4096; i += 256) {
    qs[i >> 7][i & 127] = qb[i];
    ks[i >> 7][i & 127] = kb[i];
  }
  __syncthreads();
  const float scale = 0.088388347648318447f;  // 1/sqrt(128)
#pragma unroll
  for (int tI = 0; tI < 4; ++tI) {
    int t = tid + tI * 256;
    int i = t >> 5, j = t & 31;
    float s = 0.f;
    for (int e = 0; e < 128; ++e) s = fmaf(qs[i][e], ks[j][e], s);
    p[i][j] = (i == j) ? -1e9f : s * scale;
  }
  __syncthreads();
  if (tid < 32) {
    const int i = tid;
    float m = -1e30f;
    for (int j = 0; j < 32; ++j) m = fmaxf(m, p[i][j]);
    float sum = 0.f;
    for (int j = 0; j < 32; ++j) {
      float e = expf(p[i][j] - m);
      p[i][j] = e;
      sum += e;
    }
    float inv = 1.f / sum;
    for (int j = 0; j < 32; ++j) p[i][j] *= inv;
  }
  __syncthreads();
#pragma unroll
  for (int tI = 0; tI < 4; ++tI) {
    int t = tid + tI * 256;
    int i = t >> 5, j = t & 31;
    float v = (i == j) ? 0.f : 0.5f * (p[i][j] + p[j][i]);
    a2[i][j] = v;
    attn_out[(size_t)b * 1024 + t] = v;
  }
  __syncthreads();
  if (tid < 32) {
    const int i = tid;
    float d = 0.f, en = 0.f;
    for (int j = 0; j < 32; ++j) {
      float v = a2[i][j];
      d += v;
      float c = fmaxf(v, 1e-8f);
      en -= c * logf(c);
    }
    float* srow = si + ((size_t)b * 32 + i) * 34;
    for (int j = 0; j < 32; ++j) srow[j] = a2[i][j];
    srow[32] = d;
    srow[33] = en;
  }
}

// ---------------- group assign: probs + t = sf + probs@group_emb ----------------
// One wave per row; 4 rows per 256-thread block.
__global__ __launch_bounds__(256) void group_kernel(
    const float* __restrict__ sf, const float* __restrict__ ga_w,
    const float* __restrict__ ga_b, const float* __restrict__ gemb,
    float* __restrict__ probs, float* __restrict__ tout) {
  const size_t r = (size_t)blockIdx.x * 4 + (threadIdx.x >> 6);
  const int lane = threadIdx.x & 63;
  const int e = lane * 4;
  const float4 s4 = *(const float4*)(sf + r * 256 + e);
  float lg[3];
#pragma unroll
  for (int g = 0; g < 3; ++g) {
    lg[g] = s4.x * ga_w[(e + 0) * 3 + g] + s4.y * ga_w[(e + 1) * 3 + g] +
            s4.z * ga_w[(e + 2) * 3 + g] + s4.w * ga_w[(e + 3) * 3 + g];
  }
#pragma unroll
  for (int off = 32; off; off >>= 1) {
#pragma unroll
    for (int g = 0; g < 3; ++g) lg[g] += __shfl_xor(lg[g], off, 64);
  }
#pragma unroll
  for (int g = 0; g < 3; ++g) lg[g] += ga_b[g];  // TAU = 1
  float m = fmaxf(lg[0], fmaxf(lg[1], lg[2]));
  float e0 = expf(lg[0] - m), e1 = expf(lg[1] - m), e2 = expf(lg[2] - m);
  float inv = 1.f / (e0 + e1 + e2);
  float p0 = e0 * inv, p1 = e1 * inv, p2 = e2 * inv;
  if (lane == 0) probs[r * 3 + 0] = p0;
  if (lane == 1) probs[r * 3 + 1] = p1;
  if (lane == 2) probs[r * 3 + 2] = p2;
  float4 t4;
  t4.x = s4.x + p0 * gemb[e + 0] + p1 * gemb[256 + e + 0] + p2 * gemb[512 + e + 0];
  t4.y = s4.y + p0 * gemb[e + 1] + p1 * gemb[256 + e + 1] + p2 * gemb[512 + e + 1];
  t4.z = s4.z + p0 * gemb[e + 2] + p1 * gemb[256 + e + 2] + p2 * gemb[512 + e + 2];
  t4.w = s4.w + p0 * gemb[e + 3] + p1 * gemb[256 + e + 3] + p2 * gemb[512 + e + 3];
  *(float4*)(tout + r * 256 + e) = t4;
}

// ---------------- fused hypernetwork q: never materializes fc2_w ----------------
// q[r,o] = sum_h h[r,h] * (gs[r,:]@hw_w[:,h*32+o] + hw_b[h*32+o]) + fc2_b[r,o]
// Block: 32 rows, 256 threads: og = tid&7 (4 outputs each), rg = tid>>3 (row).
__global__ __launch_bounds__(256) void hyper_q_kernel(
    const float* __restrict__ GS, const float* __restrict__ Hh,
    const float* __restrict__ Wq, const float* __restrict__ bq,
    const float* __restrict__ Wb, const float* __restrict__ bb,
    float* __restrict__ Qout) {
  __shared__ float gs_s[32][260];
  __shared__ float h_s[32][132];
  const int row0 = blockIdx.x * 32;
  const int tid = threadIdx.x;
  for (int i = tid; i < 2048; i += 256) {
    int r = i >> 6, c = (i & 63) << 2;
    *(float4*)&gs_s[r][c] = *(const float4*)(GS + (size_t)(row0 + r) * 256 + c);
  }
  for (int i = tid; i < 1024; i += 256) {
    int r = i >> 5, c = (i & 31) << 2;
    *(float4*)&h_s[r][c] = *(const float4*)(Hh + (size_t)(row0 + r) * 128 + c);
  }
  __syncthreads();
  const int og = tid & 7;
  const int rg = tid >> 3;
  const int o0 = og << 2;
  float acc0 = 0.f, acc1 = 0.f, acc2 = 0.f, acc3 = 0.f;
  for (int h0 = 0; h0 < 128; ++h0) {
    const float* wp = Wq + (size_t)h0 * 32 + o0;
    float t0 = 0.f, t1 = 0.f, t2 = 0.f, t3 = 0.f;
#pragma unroll 4
    for (int e4 = 0; e4 < 64; ++e4) {
      float4 g4 = *(const float4*)&gs_s[rg][e4 << 2];
      float4 w0 = *(const float4*)(wp + (size_t)(e4 * 4 + 0) * 4096);
      float4 w1 = *(const float4*)(wp + (size_t)(e4 * 4 + 1) * 4096);
      float4 w2 = *(const float4*)(wp + (size_t)(e4 * 4 + 2) * 4096);
      float4 w3 = *(const float4*)(wp + (size_t)(e4 * 4 + 3) * 4096);
      t0 = fmaf(g4.x, w0.x, fmaf(g4.y, w1.x, fmaf(g4.z, w2.x, fmaf(g4.w, w3.x, t0))));
      t1 = fmaf(g4.x, w0.y, fmaf(g4.y, w1.y, fmaf(g4.z, w2.y, fmaf(g4.w, w3.y, t1))));
      t2 = fmaf(g4.x, w0.z, fmaf(g4.y, w1.z, fmaf(g4.z, w2.z, fmaf(g4.w, w3.z, t2))));
      t3 = fmaf(g4.x, w0.w, fmaf(g4.y, w1.w, fmaf(g4.z, w2.w, fmaf(g4.w, w3.w, t3))));
    }
    float hv = h_s[rg][h0];
    acc0 = fmaf(hv, t0, acc0);
    acc1 = fmaf(hv, t1, acc1);
    acc2 = fmaf(hv, t2, acc2);
    acc3 = fmaf(hv, t3, acc3);
  }
  // + sum_h h[r,h]*hw_b[h*32+o]
  for (int h0 = 0; h0 < 128; ++h0) {
    float hv = h_s[rg][h0];
    float4 b4 = *(const float4*)(bq + h0 * 32 + o0);
    acc0 = fmaf(hv, b4.x, acc0);
    acc1 = fmaf(hv, b4.y, acc1);
    acc2 = fmaf(hv, b4.z, acc2);
    acc3 = fmaf(hv, b4.w, acc3);
  }
  // + fc2_b = gs@hb_w + hb_b
  for (int e = 0; e < 256; ++e) {
    float g = gs_s[rg][e];
    float4 w = *(const float4*)(Wb + e * 32 + o0);
    acc0 = fmaf(g, w.x, acc0);
    acc1 = fmaf(g, w.y, acc1);
    acc2 = fmaf(g, w.z, acc2);
    acc3 = fmaf(g, w.w, acc3);
  }
  float4 bb4 = *(const float4*)(bb + o0);
  acc0 += bb4.x;
  acc1 += bb4.y;
  acc2 += bb4.z;
  acc3 += bb4.w;
  *(float4*)(Qout + (size_t)(row0 + rg) * 32 + o0) =
      make_float4(acc0, acc1, acc2, acc3);
}

extern "C" void kernel_launch(void* const* d_in, const int* in_sizes, int n_in,
                              void* d_out, int out_size, void* d_ws, size_t ws_size,
                              hipStream_t stream) {
  const float* inputs   = (const float*)d_in[0];
  const float* hidden   = (const float*)d_in[1];
  const float* fc1_w    = (const float*)d_in[2];
  const float* fc1_b    = (const float*)d_in[3];
  const float* gru_wi   = (const float*)d_in[4];
  const float* gru_wh   = (const float*)d_in[5];
  const float* gru_bi   = (const float*)d_in[6];
  const float* gru_bh   = (const float*)d_in[7];
  const float* attn_q_w = (const float*)d_in[8];
  const float* attn_k_w = (const float*)d_in[9];
  const float* se1_w    = (const float*)d_in[10];
  const float* se1_b    = (const float*)d_in[11];
  const float* se2_w    = (const float*)d_in[12];
  const float* se2_b    = (const float*)d_in[13];
  const float* ga_w     = (const float*)d_in[14];
  const float* ga_b     = (const float*)d_in[15];
  const float* gemb     = (const float*)d_in[16];
  const float* gd1_w    = (const float*)d_in[17];
  const float* gd1_b    = (const float*)d_in[18];
  const float* gd2_w    = (const float*)d_in[19];
  const float* gd2_b    = (const float*)d_in[20];
  const float* hb_w     = (const float*)d_in[21];
  const float* hb_b     = (const float*)d_in[22];
  const float* hw_w     = (const float*)d_in[23];
  const float* hw_b     = (const float*)d_in[24];

  float* out = (float*)d_out;
  float* q_out     = out;              // [R,32]
  float* h_out     = out + 2097152;    // [R,128]
  float* gs_out    = out + 10485760;   // [R,256]
  float* probs_out = out + 27262976;   // [R,3]
  float* attn_out  = out + 27459584;   // [B,32,32]

  // workspace layout (floats); peak usage 33,554,432 floats = 128 MiB
  float* ws = (float*)d_ws;
  float* x1 = ws;              // [R,128] (dead after GRU)
  float* qp = ws;              // [R,128] (reuses x1)
  float* kp = ws + 8388608;    // [R,128]
  float* si = ws + 16777216;   // [R,34]  (dead after se1)
  float* s1 = ws;              // [R,256] (reuses qp/kp, dead after se2)
  float* t  = ws;              // [R,256] (reuses s1)
  float* g1 = ws + 16777216;   // [R,256] (reuses si)

  dim3 blk(256);
  // 1) x1 = relu(inputs @ fc1_w + fc1_b)           M=65536 N=128 K=160
  sgemm_kernel<1><<<dim3(2, 1024), blk, 0, stream>>>(inputs, fc1_w, fc1_b, x1, 65536, 128, 160);
  // 2) h = GRUCell(x1, hidden) -> h_out
  gru_kernel<<<dim3(2, 1024), blk, 0, stream>>>(x1, hidden, gru_wi, gru_wh, gru_bi, gru_bh, h_out);
  // 3) q_ = h @ attn_q_w ; k_ = h @ attn_k_w       N=128 K=128
  sgemm_kernel<0><<<dim3(2, 1024), blk, 0, stream>>>(h_out, attn_q_w, nullptr, qp, 65536, 128, 128);
  sgemm_kernel<0><<<dim3(2, 1024), blk, 0, stream>>>(h_out, attn_k_w, nullptr, kp, 65536, 128, 128);
  // 4) attention -> attn_out + struct_input (si)
  attn_kernel<<<dim3(2048), blk, 0, stream>>>(qp, kp, attn_out, si);
  // 5) s1 = relu(si @ se1_w + se1_b)               N=256 K=34
  sgemm_kernel<1><<<dim3(4, 1024), blk, 0, stream>>>(si, se1_w, se1_b, s1, 65536, 256, 34);
  // 6) struct_feat = tanh(s1 @ se2_w + se2_b) -> staged in gs_out region
  sgemm_kernel<2><<<dim3(4, 1024), blk, 0, stream>>>(s1, se2_w, se2_b, gs_out, 65536, 256, 256);
  // 7) probs (output) + t = sf + probs@group_emb
  group_kernel<<<dim3(16384), blk, 0, stream>>>(gs_out, ga_w, ga_b, gemb, probs_out, t);
  // 8) g1 = relu(t @ gd1_w + gd1_b)
  sgemm_kernel<1><<<dim3(4, 1024), blk, 0, stream>>>(t, gd1_w, gd1_b, g1, 65536, 256, 256);
  // 9) group_state = tanh(g1 @ gd2_w + gd2_b) -> gs_out (overwrites staged sf)
  sgemm_kernel<2><<<dim3(4, 1024), blk, 0, stream>>>(g1, gd2_w, gd2_b, gs_out, 65536, 256, 256);
  // 10) q = einsum(h, gs@hw_w+hw_b) + gs@hb_w+hb_b -> q_out
  hyper_q_kernel<<<dim3(2048), blk, 0, stream>>>(gs_out, h_out, hw_w, hw_b, hb_w, hb_b, q_out);
}

// Round 2
// 2039.770 us; speedup vs baseline: 4.0279x; 4.0279x over previous
//
#include <hip/hip_runtime.h>
#include <math.h>

// B=2048, A=32 -> R=65536 rows. E_IN=160, H=128, HE=256, NACT=32, G=3, TAU=1.
#define R_TOTAL 65536

typedef __attribute__((ext_vector_type(8))) short short8_t;
typedef __attribute__((ext_vector_type(4))) float f32x4_t;

__device__ __forceinline__ float sigmoidf_(float x) { return 1.f / (1.f + expf(-x)); }

__device__ __forceinline__ short f2bf(float x) {
  unsigned u = __float_as_uint(x);
  u += 0x7fff + ((u >> 16) & 1);   // round-to-nearest-even
  return (short)(u >> 16);
}
__device__ __forceinline__ float bf2f(short s) {
  return __uint_as_float(((unsigned)(unsigned short)s) << 16);
}

// ---------------- generic SGEMM: C = act(A[M,K] @ B[K,N] + bias) ----------------
template <int ACT>
__global__ __launch_bounds__(256) void sgemm_kernel(
    const float* __restrict__ A, const float* __restrict__ B,
    const float* __restrict__ bias, float* __restrict__ C,
    int M, int N, int K) {
  __shared__ float As[16][68];
  __shared__ float Bs[16][68];
  const int row0 = blockIdx.y * 64;
  const int col0 = blockIdx.x * 64;
  const int tid = threadIdx.x;
  const int tr = tid >> 4, tc = tid & 15;
  float acc[4][4] = {};
  for (int k0 = 0; k0 < K; k0 += 16) {
#pragma unroll
    for (int i = 0; i < 4; ++i) {
      int idx = tid + i * 256;
      int m = idx >> 4, k = idx & 15;
      As[k][m] = (k0 + k < K) ? A[(size_t)(row0 + m) * K + k0 + k] : 0.f;
    }
#pragma unroll
    for (int i = 0; i < 4; ++i) {
      int idx = tid + i * 256;
      int k = idx >> 6, n = idx & 63;
      Bs[k][n] = (k0 + k < K) ? B[(size_t)(k0 + k) * N + col0 + n] : 0.f;
    }
    __syncthreads();
#pragma unroll
    for (int k = 0; k < 16; ++k) {
      float4 a4 = *(const float4*)&As[k][tr * 4];
      float4 b4 = *(const float4*)&Bs[k][tc * 4];
      float a[4] = {a4.x, a4.y, a4.z, a4.w};
      float b[4] = {b4.x, b4.y, b4.z, b4.w};
#pragma unroll
      for (int i = 0; i < 4; ++i)
#pragma unroll
        for (int j = 0; j < 4; ++j) acc[i][j] = fmaf(a[i], b[j], acc[i][j]);
    }
    __syncthreads();
  }
#pragma unroll
  for (int i = 0; i < 4; ++i) {
    const size_t r = row0 + tr * 4 + i;
#pragma unroll
    for (int j = 0; j < 4; ++j) {
      int c = col0 + tc * 4 + j;
      float v = acc[i][j] + (bias ? bias[c] : 0.f);
      if (ACT == 1) v = fmaxf(v, 0.f);
      if (ACT == 2) v = tanhf(v);
      C[r * N + c] = v;
    }
  }
}

// ---------------- fused GRU ----------------
__global__ __launch_bounds__(256) void gru_kernel(
    const float* __restrict__ X, const float* __restrict__ Hin,
    const float* __restrict__ Wi, const float* __restrict__ Wh,
    const float* __restrict__ bi, const float* __restrict__ bh,
    float* __restrict__ Hout) {
  __shared__ float Xs[16][68];
  __shared__ float Hs[16][68];
  __shared__ float Wis[16][196];
  __shared__ float Whs[16][196];
  const int row0 = blockIdx.y * 64;
  const int j0 = blockIdx.x * 64;
  const int tid = threadIdx.x;
  const int tr = tid >> 4, tc = tid & 15;
  float acc_r[4][4] = {}, acc_z[4][4] = {}, acc_in[4][4] = {}, acc_hn[4][4] = {};
  for (int k0 = 0; k0 < 128; k0 += 16) {
#pragma unroll
    for (int i = 0; i < 4; ++i) {
      int idx = tid + i * 256;
      int m = idx >> 4, k = idx & 15;
      Xs[k][m] = X[(size_t)(row0 + m) * 128 + k0 + k];
      Hs[k][m] = Hin[(size_t)(row0 + m) * 128 + k0 + k];
    }
#pragma unroll
    for (int i = 0; i < 12; ++i) {
      int idx = tid + i * 256;
      int k = idx / 192, c = idx % 192;
      int col = ((c >> 6) << 7) + j0 + (c & 63);
      Wis[k][c] = Wi[(size_t)(k0 + k) * 384 + col];
      Whs[k][c] = Wh[(size_t)(k0 + k) * 384 + col];
    }
    __syncthreads();
#pragma unroll
    for (int k = 0; k < 16; ++k) {
      float4 xa = *(const float4*)&Xs[k][tr * 4];
      float4 ha = *(const float4*)&Hs[k][tr * 4];
      float x[4] = {xa.x, xa.y, xa.z, xa.w};
      float hh[4] = {ha.x, ha.y, ha.z, ha.w};
      float4 v;
      v = *(const float4*)&Wis[k][tc * 4];
      float wri[4] = {v.x, v.y, v.z, v.w};
      v = *(const float4*)&Wis[k][64 + tc * 4];
      float wzi[4] = {v.x, v.y, v.z, v.w};
      v = *(const float4*)&Wis[k][128 + tc * 4];
      float wni[4] = {v.x, v.y, v.z, v.w};
      v = *(const float4*)&Whs[k][tc * 4];
      float wrh[4] = {v.x, v.y, v.z, v.w};
      v = *(const float4*)&Whs[k][64 + tc * 4];
      float wzh[4] = {v.x, v.y, v.z, v.w};
      v = *(const float4*)&Whs[k][128 + tc * 4];
      float wnh[4] = {v.x, v.y, v.z, v.w};
#pragma unroll
      for (int i = 0; i < 4; ++i)
#pragma unroll
        for (int j = 0; j < 4; ++j) {
          acc_r[i][j] = fmaf(x[i], wri[j], fmaf(hh[i], wrh[j], acc_r[i][j]));
          acc_z[i][j] = fmaf(x[i], wzi[j], fmaf(hh[i], wzh[j], acc_z[i][j]));
          acc_in[i][j] = fmaf(x[i], wni[j], acc_in[i][j]);
          acc_hn[i][j] = fmaf(hh[i], wnh[j], acc_hn[i][j]);
        }
    }
    __syncthreads();
  }
#pragma unroll
  for (int i = 0; i < 4; ++i) {
    const size_t r = row0 + tr * 4 + i;
    float4 hin4 = *(const float4*)&Hin[r * 128 + j0 + tc * 4];
    float hinv[4] = {hin4.x, hin4.y, hin4.z, hin4.w};
    float o[4];
#pragma unroll
    for (int j = 0; j < 4; ++j) {
      int col = j0 + tc * 4 + j;
      float rg = sigmoidf_(acc_r[i][j] + bi[col] + bh[col]);
      float zg = sigmoidf_(acc_z[i][j] + bi[128 + col] + bh[128 + col]);
      float ng = tanhf(acc_in[i][j] + bi[256 + col] + rg * (acc_hn[i][j] + bh[256 + col]));
      o[j] = (1.f - zg) * ng + zg * hinv[j];
    }
    *(float4*)&Hout[r * 128 + j0 + tc * 4] = make_float4(o[0], o[1], o[2], o[3]);
  }
}

// ---------------- attention block ----------------
__global__ __launch_bounds__(256) void attn_kernel(
    const float* __restrict__ Qp, const float* __restrict__ Kp,
    float* __restrict__ attn_out, float* __restrict__ si) {
  __shared__ float qs[32][129];
  __shared__ float ks[32][129];
  __shared__ float p[32][33];
  __shared__ float a2[32][33];
  const int b = blockIdx.x;
  const int tid = threadIdx.x;
  const float* qb = Qp + (size_t)b * 4096;
  const float* kb = Kp + (size_t)b * 4096;
  for (int i = tid; i < 4096; i += 256) {
    qs[i >> 7][i & 127] = qb[i];
    ks[i >> 7][i & 127] = kb[i];
  }
  __syncthreads();
  const float scale = 0.088388347648318447f;
#pragma unroll
  for (int tI = 0; tI < 4; ++tI) {
    int t = tid + tI * 256;
    int i = t >> 5, j = t & 31;
    float s = 0.f;
    for (int e = 0; e < 128; ++e) s = fmaf(qs[i][e], ks[j][e], s);
    p[i][j] = (i == j) ? -1e9f : s * scale;
  }
  __syncthreads();
  if (tid < 32) {
    const int i = tid;
    float m = -1e30f;
    for (int j = 0; j < 32; ++j) m = fmaxf(m, p[i][j]);
    float sum = 0.f;
    for (int j = 0; j < 32; ++j) {
      float e = expf(p[i][j] - m);
      p[i][j] = e;
      sum += e;
    }
    float inv = 1.f / sum;
    for (int j = 0; j < 32; ++j) p[i][j] *= inv;
  }
  __syncthreads();
#pragma unroll
  for (int tI = 0; tI < 4; ++tI) {
    int t = tid + tI * 256;
    int i = t >> 5, j = t & 31;
    float v = (i == j) ? 0.f : 0.5f * (p[i][j] + p[j][i]);
    a2[i][j] = v;
    attn_out[(size_t)b * 1024 + t] = v;
  }
  __syncthreads();
  if (tid < 32) {
    const int i = tid;
    float d = 0.f, en = 0.f;
    for (int j = 0; j < 32; ++j) {
      float v = a2[i][j];
      d += v;
      float c = fmaxf(v, 1e-8f);
      en -= c * logf(c);
    }
    float* srow = si + ((size_t)b * 32 + i) * 34;
    for (int j = 0; j < 32; ++j) srow[j] = a2[i][j];
    srow[32] = d;
    srow[33] = en;
  }
}

// ---------------- group assign ----------------
__global__ __launch_bounds__(256) void group_kernel(
    const float* __restrict__ sf, const float* __restrict__ ga_w,
    const float* __restrict__ ga_b, const float* __restrict__ gemb,
    float* __restrict__ probs, float* __restrict__ tout) {
  const size_t r = (size_t)blockIdx.x * 4 + (threadIdx.x >> 6);
  const int lane = threadIdx.x & 63;
  const int e = lane * 4;
  const float4 s4 = *(const float4*)(sf + r * 256 + e);
  float lg[3];
#pragma unroll
  for (int g = 0; g < 3; ++g) {
    lg[g] = s4.x * ga_w[(e + 0) * 3 + g] + s4.y * ga_w[(e + 1) * 3 + g] +
            s4.z * ga_w[(e + 2) * 3 + g] + s4.w * ga_w[(e + 3) * 3 + g];
  }
#pragma unroll
  for (int off = 32; off; off >>= 1) {
#pragma unroll
    for (int g = 0; g < 3; ++g) lg[g] += __shfl_xor(lg[g], off, 64);
  }
#pragma unroll
  for (int g = 0; g < 3; ++g) lg[g] += ga_b[g];
  float m = fmaxf(lg[0], fmaxf(lg[1], lg[2]));
  float e0 = expf(lg[0] - m), e1 = expf(lg[1] - m), e2 = expf(lg[2] - m);
  float inv = 1.f / (e0 + e1 + e2);
  float p0 = e0 * inv, p1 = e1 * inv, p2 = e2 * inv;
  if (lane == 0) probs[r * 3 + 0] = p0;
  if (lane == 1) probs[r * 3 + 1] = p1;
  if (lane == 2) probs[r * 3 + 2] = p2;
  float4 t4;
  t4.x = s4.x + p0 * gemb[e + 0] + p1 * gemb[256 + e + 0] + p2 * gemb[512 + e + 0];
  t4.y = s4.y + p0 * gemb[e + 1] + p1 * gemb[256 + e + 1] + p2 * gemb[512 + e + 1];
  t4.z = s4.z + p0 * gemb[e + 2] + p1 * gemb[256 + e + 2] + p2 * gemb[512 + e + 2];
  t4.w = s4.w + p0 * gemb[e + 3] + p1 * gemb[256 + e + 3] + p2 * gemb[512 + e + 3];
  *(float4*)(tout + r * 256 + e) = t4;
}

// ---------------- pack hw_w into B-fragment-ordered bf16 hi/lo ----------------
// hw_w fp32 [256 e][4096 col] -> frag layout: lane l holds B[k=(l>>4)*8+i][col=ct*16+(l&15)]
// packed idx = ((ct*8 + kk)*64 + lane)*8 + i   (kk = e>>5)
__global__ __launch_bounds__(256) void pack_w_kernel(
    const float* __restrict__ W, short* __restrict__ Whi, short* __restrict__ Wlo) {
  int idx = blockIdx.x * 256 + threadIdx.x;  // 1,048,576 elements
  float w = W[idx];
  short hi = f2bf(w);
  short lo = f2bf(w - bf2f(hi));
  int e = idx >> 12, c = idx & 4095;
  int ct = c >> 4, cl = c & 15, kk = e >> 5, kgrp = (e >> 3) & 3, i = e & 7;
  size_t o = ((((size_t)ct * 8 + kk) * 64) + (kgrp * 16 + cl)) * 8 + i;
  Whi[o] = hi;
  Wlo[o] = lo;
}

// ---------------- bias part of q: gs@hb_w + h@hw_b(as [128][32]) + hb_b ----------------
__global__ __launch_bounds__(256) void biasq_kernel(
    const float* __restrict__ GS, const float* __restrict__ Hh,
    const float* __restrict__ hbw, const float* __restrict__ hbb,
    const float* __restrict__ hwb, float* __restrict__ Bq) {
  int t = blockIdx.x * 256 + threadIdx.x;  // 2,097,152
  int r = t >> 5, o = t & 31;
  const float* g = GS + (size_t)r * 256;
  const float* hp = Hh + (size_t)r * 128;
  float s = hbb[o];
#pragma unroll 4
  for (int e = 0; e < 256; ++e) s = fmaf(g[e], hbw[e * 32 + o], s);
#pragma unroll 4
  for (int k = 0; k < 128; ++k) s = fmaf(hp[k], hwb[k * 32 + o], s);
  Bq[t] = s;
}

// ---------------- MFMA hypernet q: split-bf16, never materializes fc2_w ----------------
// Block: 64 rows, 512 threads (8 waves). Wave w, chunk c: cols [c*512+w*64, +64).
// P[64,64] accumulated via mfma_f32_16x16x32_bf16 (hi*hi + hi*lo + lo*hi),
// contracted immediately with h (fp32) into per-wave q partials; LDS-reduced.
__global__ __launch_bounds__(512) void hyper_q_mfma_kernel(
    const float* __restrict__ GS, const float* __restrict__ Hh,
    const short* __restrict__ Whi, const short* __restrict__ Wlo,
    const float* __restrict__ Bq, float* __restrict__ Qout) {
  __shared__ short As_hi[64 * 256];   // 32 KB, XOR-swizzled
  __shared__ short As_lo[64 * 256];   // 32 KB
  __shared__ float Hs[64 * 128];      // 32 KB
  __shared__ float Qred[64 * 32];     // 8 KB
  const int tid = threadIdx.x;
  const int row0 = blockIdx.x * 64;

  // stage gs -> bf16 hi/lo (swizzled: byte ^= (row&7)<<4 within row's 512B)
  for (int f = tid; f < 2048; f += 512) {
    int row = f >> 5, eg = f & 31;
    const float* src = GS + (size_t)(row0 + row) * 256 + eg * 8;
    float4 v0 = *(const float4*)src;
    float4 v1 = *(const float4*)(src + 4);
    float vs[8] = {v0.x, v0.y, v0.z, v0.w, v1.x, v1.y, v1.z, v1.w};
    short8_t sh, sl;
#pragma unroll
    for (int i = 0; i < 8; ++i) {
      short h = f2bf(vs[i]);
      sh[i] = h;
      sl[i] = f2bf(vs[i] - bf2f(h));
    }
    int addr = (row * 512 + eg * 16) ^ ((row & 7) << 4);
    *(short8_t*)((char*)As_hi + addr) = sh;
    *(short8_t*)((char*)As_lo + addr) = sl;
  }
  for (int i = tid; i < 8192; i += 512) Hs[i] = Hh[(size_t)row0 * 128 + i];
  for (int i = tid; i < 2048; i += 512) Qred[i] = 0.f;
  __syncthreads();

  const int wave = tid >> 6, lane = tid & 63;
  const int cl = lane & 15, kg = lane >> 4;
  float qf[4][2][4] = {};

  for (int c = 0; c < 8; ++c) {
    f32x4_t acc[4][4];
#pragma unroll
    for (int m = 0; m < 4; ++m)
#pragma unroll
      for (int n = 0; n < 4; ++n) acc[m][n] = (f32x4_t){0.f, 0.f, 0.f, 0.f};

    for (int kk = 0; kk < 8; ++kk) {
      short8_t ah[4], al[4];
#pragma unroll
      for (int m = 0; m < 4; ++m) {
        int row = m * 16 + cl;
        int addr = (row * 512 + kk * 64 + kg * 16) ^ ((row & 7) << 4);
        ah[m] = *(const short8_t*)((const char*)As_hi + addr);
        al[m] = *(const short8_t*)((const char*)As_lo + addr);
      }
#pragma unroll
      for (int n = 0; n < 4; ++n) {
        int ct = c * 32 + wave * 4 + n;
        size_t boff = (((size_t)ct * 8 + kk) * 64 + lane) * 8;
        short8_t bh = *(const short8_t*)(Whi + boff);
        short8_t bl = *(const short8_t*)(Wlo + boff);
#pragma unroll
        for (int m = 0; m < 4; ++m) {
          acc[m][n] = __builtin_amdgcn_mfma_f32_16x16x32_bf16(ah[m], bh, acc[m][n], 0, 0, 0);
          acc[m][n] = __builtin_amdgcn_mfma_f32_16x16x32_bf16(ah[m], bl, acc[m][n], 0, 0, 0);
          acc[m][n] = __builtin_amdgcn_mfma_f32_16x16x32_bf16(al[m], bh, acc[m][n], 0, 0, 0);
        }
      }
    }
    // contract P chunk with h: col = c*512 + wave*64 + n*16 + cl -> h = c*16+wave*2+(n>>1), o = (n&1)*16+cl
#pragma unroll
    for (int half = 0; half < 2; ++half) {
      int hl = c * 16 + wave * 2 + half;
#pragma unroll
      for (int m = 0; m < 4; ++m)
#pragma unroll
        for (int j = 0; j < 4; ++j) {
          float hv = Hs[(m * 16 + kg * 4 + j) * 128 + hl];
          qf[m][0][j] = fmaf(hv, acc[m][half * 2 + 0][j], qf[m][0][j]);
          qf[m][1][j] = fmaf(hv, acc[m][half * 2 + 1][j], qf[m][1][j]);
        }
    }
  }
  // cross-wave reduce
#pragma unroll
  for (int m = 0; m < 4; ++m)
#pragma unroll
    for (int oh = 0; oh < 2; ++oh)
#pragma unroll
      for (int j = 0; j < 4; ++j) {
        int row = m * 16 + kg * 4 + j, o = oh * 16 + cl;
        atomicAdd(&Qred[row * 32 + o], qf[m][oh][j]);
      }
  __syncthreads();
  for (int i = tid; i < 2048; i += 512) {
    size_t gi = (size_t)row0 * 32 + i;
    Qout[gi] = Qred[i] + Bq[gi];
  }
}

extern "C" void kernel_launch(void* const* d_in, const int* in_sizes, int n_in,
                              void* d_out, int out_size, void* d_ws, size_t ws_size,
                              hipStream_t stream) {
  const float* inputs   = (const float*)d_in[0];
  const float* hidden   = (const float*)d_in[1];
  const float* fc1_w    = (const float*)d_in[2];
  const float* fc1_b    = (const float*)d_in[3];
  const float* gru_wi   = (const float*)d_in[4];
  const float* gru_wh   = (const float*)d_in[5];
  const float* gru_bi   = (const float*)d_in[6];
  const float* gru_bh   = (const float*)d_in[7];
  const float* attn_q_w = (const float*)d_in[8];
  const float* attn_k_w = (const float*)d_in[9];
  const float* se1_w    = (const float*)d_in[10];
  const float* se1_b    = (const float*)d_in[11];
  const float* se2_w    = (const float*)d_in[12];
  const float* se2_b    = (const float*)d_in[13];
  const float* ga_w     = (const float*)d_in[14];
  const float* ga_b     = (const float*)d_in[15];
  const float* gemb     = (const float*)d_in[16];
  const float* gd1_w    = (const float*)d_in[17];
  const float* gd1_b    = (const float*)d_in[18];
  const float* gd2_w    = (const float*)d_in[19];
  const float* gd2_b    = (const float*)d_in[20];
  const float* hb_w     = (const float*)d_in[21];
  const float* hb_b     = (const float*)d_in[22];
  const float* hw_w     = (const float*)d_in[23];
  const float* hw_b     = (const float*)d_in[24];

  float* out = (float*)d_out;
  float* q_out     = out;              // [R,32]
  float* h_out     = out + 2097152;    // [R,128]
  float* gs_out    = out + 10485760;   // [R,256]
  float* probs_out = out + 27262976;   // [R,3]
  float* attn_out  = out + 27459584;   // [B,32,32]

  // workspace (floats). Region A = ws[0 .. 16.7M) (64MB), Region B = ws[16.7M .. 33.5M).
  float* ws = (float*)d_ws;
  float* x1 = ws;              // [R,128] (A; dead after GRU)
  float* qp = ws;              // [R,128] (A)
  float* kp = ws + 8388608;    // [R,128] (A)
  float* si = ws + 16777216;   // [R,34]  (B; dead after se1)
  float* s1 = ws;              // [R,256] (A; dead after se2)
  float* t  = ws;              // [R,256] (A; dead after gd1)
  float* g1 = ws + 16777216;   // [R,256] (B; dead after gd2)
  // After gd1, region A is dead -> reuse for hyper-q scratch:
  float* biasq = ws;                                        // [R,32] = 8 MB (bytes 0-8M)
  short* Whi = (short*)((char*)d_ws + (size_t)8 * 1024 * 1024);   // 2 MB (bytes 8-10M)
  short* Wlo = (short*)((char*)d_ws + (size_t)10 * 1024 * 1024);  // 2 MB (bytes 10-12M)

  dim3 blk(256);
  // 1) x1 = relu(inputs @ fc1_w + fc1_b)
  sgemm_kernel<1><<<dim3(2, 1024), blk, 0, stream>>>(inputs, fc1_w, fc1_b, x1, 65536, 128, 160);
  // 2) h = GRUCell(x1, hidden)
  gru_kernel<<<dim3(2, 1024), blk, 0, stream>>>(x1, hidden, gru_wi, gru_wh, gru_bi, gru_bh, h_out);
  // 3) q_/k_ projections
  sgemm_kernel<0><<<dim3(2, 1024), blk, 0, stream>>>(h_out, attn_q_w, nullptr, qp, 65536, 128, 128);
  sgemm_kernel<0><<<dim3(2, 1024), blk, 0, stream>>>(h_out, attn_k_w, nullptr, kp, 65536, 128, 128);
  // 4) attention -> attn_out + struct_input
  attn_kernel<<<dim3(2048), blk, 0, stream>>>(qp, kp, attn_out, si);
  // 5) s1 = relu(si @ se1_w + se1_b)
  sgemm_kernel<1><<<dim3(4, 1024), blk, 0, stream>>>(si, se1_w, se1_b, s1, 65536, 256, 34);
  // 6) struct_feat -> staged in gs_out
  sgemm_kernel<2><<<dim3(4, 1024), blk, 0, stream>>>(s1, se2_w, se2_b, gs_out, 65536, 256, 256);
  // 7) probs + t
  group_kernel<<<dim3(16384), blk, 0, stream>>>(gs_out, ga_w, ga_b, gemb, probs_out, t);
  // 8) g1 = relu(t @ gd1_w + gd1_b)   (last reader of region A)
  sgemm_kernel<1><<<dim3(4, 1024), blk, 0, stream>>>(t, gd1_w, gd1_b, g1, 65536, 256, 256);
  // 8.5) pack hw_w -> fragment-ordered bf16 hi/lo (region A now free)
  pack_w_kernel<<<dim3(4096), blk, 0, stream>>>(hw_w, Whi, Wlo);
  // 9) group_state = tanh(g1 @ gd2_w + gd2_b) -> gs_out
  sgemm_kernel<2><<<dim3(4, 1024), blk, 0, stream>>>(g1, gd2_w, gd2_b, gs_out, 65536, 256, 256);
  // 9.5) bias part of q
  biasq_kernel<<<dim3(8192), blk, 0, stream>>>(gs_out, h_out, hb_w, hb_b, hw_b, biasq);
  // 10) q via MFMA split-bf16
  hyper_q_mfma_kernel<<<dim3(1024), dim3(512), 0, stream>>>(gs_out, h_out, Whi, Wlo, biasq, q_out);
}

// Round 3
// 1510.481 us; speedup vs baseline: 5.4393x; 1.3504x over previous
//
#include <hip/hip_runtime.h>
#include <math.h>

// B=2048, A=32 -> R=65536 rows. E_IN=160, H=128, HE=256, NACT=32, G=3, TAU=1.
#define R_TOTAL 65536

typedef __attribute__((ext_vector_type(8))) short short8_t;
typedef __attribute__((ext_vector_type(4))) float f32x4_t;

__device__ __forceinline__ float sigmoidf_(float x) { return 1.f / (1.f + expf(-x)); }

__device__ __forceinline__ short f2bf(float x) {
  unsigned u = __float_as_uint(x);
  u += 0x7fff + ((u >> 16) & 1);   // round-to-nearest-even
  return (short)(u >> 16);
}
__device__ __forceinline__ float bf2f(short s) {
  return __uint_as_float(((unsigned)(unsigned short)s) << 16);
}

// ---------------- generic SGEMM: C = act(A[M,K] @ B[K,N] + bias) ----------------
template <int ACT>
__global__ __launch_bounds__(256) void sgemm_kernel(
    const float* __restrict__ A, const float* __restrict__ B,
    const float* __restrict__ bias, float* __restrict__ C,
    int M, int N, int K) {
  __shared__ float As[16][68];
  __shared__ float Bs[16][68];
  const int row0 = blockIdx.y * 64;
  const int col0 = blockIdx.x * 64;
  const int tid = threadIdx.x;
  const int tr = tid >> 4, tc = tid & 15;
  float acc[4][4] = {};
  for (int k0 = 0; k0 < K; k0 += 16) {
#pragma unroll
    for (int i = 0; i < 4; ++i) {
      int idx = tid + i * 256;
      int m = idx >> 4, k = idx & 15;
      As[k][m] = (k0 + k < K) ? A[(size_t)(row0 + m) * K + k0 + k] : 0.f;
    }
#pragma unroll
    for (int i = 0; i < 4; ++i) {
      int idx = tid + i * 256;
      int k = idx >> 6, n = idx & 63;
      Bs[k][n] = (k0 + k < K) ? B[(size_t)(k0 + k) * N + col0 + n] : 0.f;
    }
    __syncthreads();
#pragma unroll
    for (int k = 0; k < 16; ++k) {
      float4 a4 = *(const float4*)&As[k][tr * 4];
      float4 b4 = *(const float4*)&Bs[k][tc * 4];
      float a[4] = {a4.x, a4.y, a4.z, a4.w};
      float b[4] = {b4.x, b4.y, b4.z, b4.w};
#pragma unroll
      for (int i = 0; i < 4; ++i)
#pragma unroll
        for (int j = 0; j < 4; ++j) acc[i][j] = fmaf(a[i], b[j], acc[i][j]);
    }
    __syncthreads();
  }
#pragma unroll
  for (int i = 0; i < 4; ++i) {
    const size_t r = row0 + tr * 4 + i;
#pragma unroll
    for (int j = 0; j < 4; ++j) {
      int c = col0 + tc * 4 + j;
      float v = acc[i][j] + (bias ? bias[c] : 0.f);
      if (ACT == 1) v = fmaxf(v, 0.f);
      if (ACT == 2) v = tanhf(v);
      C[r * N + c] = v;
    }
  }
}

// ---------------- fused GRU ----------------
__global__ __launch_bounds__(256) void gru_kernel(
    const float* __restrict__ X, const float* __restrict__ Hin,
    const float* __restrict__ Wi, const float* __restrict__ Wh,
    const float* __restrict__ bi, const float* __restrict__ bh,
    float* __restrict__ Hout) {
  __shared__ float Xs[16][68];
  __shared__ float Hs[16][68];
  __shared__ float Wis[16][196];
  __shared__ float Whs[16][196];
  const int row0 = blockIdx.y * 64;
  const int j0 = blockIdx.x * 64;
  const int tid = threadIdx.x;
  const int tr = tid >> 4, tc = tid & 15;
  float acc_r[4][4] = {}, acc_z[4][4] = {}, acc_in[4][4] = {}, acc_hn[4][4] = {};
  for (int k0 = 0; k0 < 128; k0 += 16) {
#pragma unroll
    for (int i = 0; i < 4; ++i) {
      int idx = tid + i * 256;
      int m = idx >> 4, k = idx & 15;
      Xs[k][m] = X[(size_t)(row0 + m) * 128 + k0 + k];
      Hs[k][m] = Hin[(size_t)(row0 + m) * 128 + k0 + k];
    }
#pragma unroll
    for (int i = 0; i < 12; ++i) {
      int idx = tid + i * 256;
      int k = idx / 192, c = idx % 192;
      int col = ((c >> 6) << 7) + j0 + (c & 63);
      Wis[k][c] = Wi[(size_t)(k0 + k) * 384 + col];
      Whs[k][c] = Wh[(size_t)(k0 + k) * 384 + col];
    }
    __syncthreads();
#pragma unroll
    for (int k = 0; k < 16; ++k) {
      float4 xa = *(const float4*)&Xs[k][tr * 4];
      float4 ha = *(const float4*)&Hs[k][tr * 4];
      float x[4] = {xa.x, xa.y, xa.z, xa.w};
      float hh[4] = {ha.x, ha.y, ha.z, ha.w};
      float4 v;
      v = *(const float4*)&Wis[k][tc * 4];
      float wri[4] = {v.x, v.y, v.z, v.w};
      v = *(const float4*)&Wis[k][64 + tc * 4];
      float wzi[4] = {v.x, v.y, v.z, v.w};
      v = *(const float4*)&Wis[k][128 + tc * 4];
      float wni[4] = {v.x, v.y, v.z, v.w};
      v = *(const float4*)&Whs[k][tc * 4];
      float wrh[4] = {v.x, v.y, v.z, v.w};
      v = *(const float4*)&Whs[k][64 + tc * 4];
      float wzh[4] = {v.x, v.y, v.z, v.w};
      v = *(const float4*)&Whs[k][128 + tc * 4];
      float wnh[4] = {v.x, v.y, v.z, v.w};
#pragma unroll
      for (int i = 0; i < 4; ++i)
#pragma unroll
        for (int j = 0; j < 4; ++j) {
          acc_r[i][j] = fmaf(x[i], wri[j], fmaf(hh[i], wrh[j], acc_r[i][j]));
          acc_z[i][j] = fmaf(x[i], wzi[j], fmaf(hh[i], wzh[j], acc_z[i][j]));
          acc_in[i][j] = fmaf(x[i], wni[j], acc_in[i][j]);
          acc_hn[i][j] = fmaf(hh[i], wnh[j], acc_hn[i][j]);
        }
    }
    __syncthreads();
  }
#pragma unroll
  for (int i = 0; i < 4; ++i) {
    const size_t r = row0 + tr * 4 + i;
    float4 hin4 = *(const float4*)&Hin[r * 128 + j0 + tc * 4];
    float hinv[4] = {hin4.x, hin4.y, hin4.z, hin4.w};
    float o[4];
#pragma unroll
    for (int j = 0; j < 4; ++j) {
      int col = j0 + tc * 4 + j;
      float rg = sigmoidf_(acc_r[i][j] + bi[col] + bh[col]);
      float zg = sigmoidf_(acc_z[i][j] + bi[128 + col] + bh[128 + col]);
      float ng = tanhf(acc_in[i][j] + bi[256 + col] + rg * (acc_hn[i][j] + bh[256 + col]));
      o[j] = (1.f - zg) * ng + zg * hinv[j];
    }
    *(float4*)&Hout[r * 128 + j0 + tc * 4] = make_float4(o[0], o[1], o[2], o[3]);
  }
}

// ---------------- attention block ----------------
__global__ __launch_bounds__(256) void attn_kernel(
    const float* __restrict__ Qp, const float* __restrict__ Kp,
    float* __restrict__ attn_out, float* __restrict__ si) {
  __shared__ float qs[32][129];
  __shared__ float ks[32][129];
  __shared__ float p[32][33];
  __shared__ float a2[32][33];
  const int b = blockIdx.x;
  const int tid = threadIdx.x;
  const float* qb = Qp + (size_t)b * 4096;
  const float* kb = Kp + (size_t)b * 4096;
  for (int i = tid; i < 4096; i += 256) {
    qs[i >> 7][i & 127] = qb[i];
    ks[i >> 7][i & 127] = kb[i];
  }
  __syncthreads();
  const float scale = 0.088388347648318447f;
#pragma unroll
  for (int tI = 0; tI < 4; ++tI) {
    int t = tid + tI * 256;
    int i = t >> 5, j = t & 31;
    float s = 0.f;
    for (int e = 0; e < 128; ++e) s = fmaf(qs[i][e], ks[j][e], s);
    p[i][j] = (i == j) ? -1e9f : s * scale;
  }
  __syncthreads();
  if (tid < 32) {
    const int i = tid;
    float m = -1e30f;
    for (int j = 0; j < 32; ++j) m = fmaxf(m, p[i][j]);
    float sum = 0.f;
    for (int j = 0; j < 32; ++j) {
      float e = expf(p[i][j] - m);
      p[i][j] = e;
      sum += e;
    }
    float inv = 1.f / sum;
    for (int j = 0; j < 32; ++j) p[i][j] *= inv;
  }
  __syncthreads();
#pragma unroll
  for (int tI = 0; tI < 4; ++tI) {
    int t = tid + tI * 256;
    int i = t >> 5, j = t & 31;
    float v = (i == j) ? 0.f : 0.5f * (p[i][j] + p[j][i]);
    a2[i][j] = v;
    attn_out[(size_t)b * 1024 + t] = v;
  }
  __syncthreads();
  if (tid < 32) {
    const int i = tid;
    float d = 0.f, en = 0.f;
    for (int j = 0; j < 32; ++j) {
      float v = a2[i][j];
      d += v;
      float c = fmaxf(v, 1e-8f);
      en -= c * logf(c);
    }
    float* srow = si + ((size_t)b * 32 + i) * 34;
    for (int j = 0; j < 32; ++j) srow[j] = a2[i][j];
    srow[32] = d;
    srow[33] = en;
  }
}

// ---------------- group assign ----------------
__global__ __launch_bounds__(256) void group_kernel(
    const float* __restrict__ sf, const float* __restrict__ ga_w,
    const float* __restrict__ ga_b, const float* __restrict__ gemb,
    float* __restrict__ probs, float* __restrict__ tout) {
  const size_t r = (size_t)blockIdx.x * 4 + (threadIdx.x >> 6);
  const int lane = threadIdx.x & 63;
  const int e = lane * 4;
  const float4 s4 = *(const float4*)(sf + r * 256 + e);
  float lg[3];
#pragma unroll
  for (int g = 0; g < 3; ++g) {
    lg[g] = s4.x * ga_w[(e + 0) * 3 + g] + s4.y * ga_w[(e + 1) * 3 + g] +
            s4.z * ga_w[(e + 2) * 3 + g] + s4.w * ga_w[(e + 3) * 3 + g];
  }
#pragma unroll
  for (int off = 32; off; off >>= 1) {
#pragma unroll
    for (int g = 0; g < 3; ++g) lg[g] += __shfl_xor(lg[g], off, 64);
  }
#pragma unroll
  for (int g = 0; g < 3; ++g) lg[g] += ga_b[g];
  float m = fmaxf(lg[0], fmaxf(lg[1], lg[2]));
  float e0 = expf(lg[0] - m), e1 = expf(lg[1] - m), e2 = expf(lg[2] - m);
  float inv = 1.f / (e0 + e1 + e2);
  float p0 = e0 * inv, p1 = e1 * inv, p2 = e2 * inv;
  if (lane == 0) probs[r * 3 + 0] = p0;
  if (lane == 1) probs[r * 3 + 1] = p1;
  if (lane == 2) probs[r * 3 + 2] = p2;
  float4 t4;
  t4.x = s4.x + p0 * gemb[e + 0] + p1 * gemb[256 + e + 0] + p2 * gemb[512 + e + 0];
  t4.y = s4.y + p0 * gemb[e + 1] + p1 * gemb[256 + e + 1] + p2 * gemb[512 + e + 1];
  t4.z = s4.z + p0 * gemb[e + 2] + p1 * gemb[256 + e + 2] + p2 * gemb[512 + e + 2];
  t4.w = s4.w + p0 * gemb[e + 3] + p1 * gemb[256 + e + 3] + p2 * gemb[512 + e + 3];
  *(float4*)(tout + r * 256 + e) = t4;
}

// ---------------- pack hw_w into B-fragment-ordered bf16 hi/lo ----------------
// packed idx = ((ct*8 + kk)*64 + lane)*8 + i ; lane=(kgrp*16+cl); e=kk*32+kgrp*8+i; col=ct*16+cl
__global__ __launch_bounds__(256) void pack_w_kernel(
    const float* __restrict__ W, short* __restrict__ Whi, short* __restrict__ Wlo) {
  int idx = blockIdx.x * 256 + threadIdx.x;  // 1,048,576 elements
  float w = W[idx];
  short hi = f2bf(w);
  short lo = f2bf(w - bf2f(hi));
  int e = idx >> 12, c = idx & 4095;
  int ct = c >> 4, cl = c & 15, kk = e >> 5, kgrp = (e >> 3) & 3, i = e & 7;
  size_t o = ((((size_t)ct * 8 + kk) * 64) + (kgrp * 16 + cl)) * 8 + i;
  Whi[o] = hi;
  Wlo[o] = lo;
}

// ---------------- bias part of q: gs@hb_w + h@hw_b(as [128][32]) + hb_b ----------------
__global__ __launch_bounds__(256) void biasq_kernel(
    const float* __restrict__ GS, const float* __restrict__ Hh,
    const float* __restrict__ hbw, const float* __restrict__ hbb,
    const float* __restrict__ hwb, float* __restrict__ Bq) {
  int t = blockIdx.x * 256 + threadIdx.x;  // 2,097,152
  int r = t >> 5, o = t & 31;
  const float* g = GS + (size_t)r * 256;
  const float* hp = Hh + (size_t)r * 128;
  float s = hbb[o];
#pragma unroll 4
  for (int e = 0; e < 256; ++e) s = fmaf(g[e], hbw[e * 32 + o], s);
#pragma unroll 4
  for (int k = 0; k < 128; ++k) s = fmaf(hp[k], hwb[k * 32 + o], s);
  Bq[t] = s;
}

// ---------------- MFMA hypernet q v2: A in registers, W through LDS dbuf ----------------
// 256 blocks x 512 threads (8 waves). Wave owns 32 rows (2 m-frags); BM=256.
// Per chunk ct (16 cols): stage next W chunk (reg->LDS), read bh/bl from LDS,
// 6 MFMAs per kk (3-split x 2 m), contract with h into qf; one barrier/chunk.
__global__ __launch_bounds__(512, 2) void hyper_q_reg_kernel(
    const float* __restrict__ GS, const float* __restrict__ Hh,
    const short* __restrict__ Whi, const short* __restrict__ Wlo,
    const float* __restrict__ Bq, float* __restrict__ Qout) {
  __shared__ short Bhi[2][4096];   // 16 KB
  __shared__ short Blo[2][4096];   // 16 KB
  const int tid = threadIdx.x;
  const int wave = tid >> 6, lane = tid & 63;
  const int cl = lane & 15, kg = lane >> 4;
  const int row0 = blockIdx.x * 256;

  // ---- A (gs) -> registers as bf16 hi/lo fragments (verified 16x16x32 layout) ----
  // m-frag row = lane&15 (+16*m); element i at e = kk*32 + kg*8 + i.
  short8_t ah0[8], al0[8], ah1[8], al1[8];
  {
    const float* a0p = GS + (size_t)(row0 + wave * 32 + cl) * 256;
    const float* a1p = a0p + 16 * 256;
#pragma unroll
    for (int kk = 0; kk < 8; ++kk) {
      float4 u0 = *(const float4*)(a0p + kk * 32 + kg * 8);
      float4 u1 = *(const float4*)(a0p + kk * 32 + kg * 8 + 4);
      float4 v0 = *(const float4*)(a1p + kk * 32 + kg * 8);
      float4 v1 = *(const float4*)(a1p + kk * 32 + kg * 8 + 4);
      float ua[8] = {u0.x, u0.y, u0.z, u0.w, u1.x, u1.y, u1.z, u1.w};
      float va[8] = {v0.x, v0.y, v0.z, v0.w, v1.x, v1.y, v1.z, v1.w};
      short8_t h0, l0, h1, l1;
#pragma unroll
      for (int i = 0; i < 8; ++i) {
        short hh = f2bf(ua[i]);
        h0[i] = hh; l0[i] = f2bf(ua[i] - bf2f(hh));
        short hv = f2bf(va[i]);
        h1[i] = hv; l1[i] = f2bf(va[i] - bf2f(hv));
      }
      ah0[kk] = h0; al0[kk] = l0; ah1[kk] = h1; al1[kk] = l1;
    }
  }

  // ---- prologue: stage chunk 0 into buf 0 ----
  {
    short8_t vh = *(const short8_t*)(Whi + tid * 8);
    short8_t vl = *(const short8_t*)(Wlo + tid * 8);
    *(short8_t*)&Bhi[0][tid * 8] = vh;
    *(short8_t*)&Blo[0][tid * 8] = vl;
  }
  __syncthreads();

  float qf0[2][4] = {};  // [oh][j] for m=0
  float qf1[2][4] = {};  // [oh][j] for m=1

#define COMPUTE_HALF(BUF, OH)                                                  \
  {                                                                            \
    f32x4_t acc0 = (f32x4_t){0.f, 0.f, 0.f, 0.f};                              \
    f32x4_t acc1 = (f32x4_t){0.f, 0.f, 0.f, 0.f};                              \
    _Pragma("unroll")                                                          \
    for (int kk = 0; kk < 8; ++kk) {                                           \
      short8_t bh = *(const short8_t*)&Bhi[BUF][(kk * 64 + lane) * 8];         \
      short8_t bl = *(const short8_t*)&Blo[BUF][(kk * 64 + lane) * 8];         \
      acc0 = __builtin_amdgcn_mfma_f32_16x16x32_bf16(ah0[kk], bh, acc0, 0, 0, 0); \
      acc0 = __builtin_amdgcn_mfma_f32_16x16x32_bf16(ah0[kk], bl, acc0, 0, 0, 0); \
      acc0 = __builtin_amdgcn_mfma_f32_16x16x32_bf16(al0[kk], bh, acc0, 0, 0, 0); \
      acc1 = __builtin_amdgcn_mfma_f32_16x16x32_bf16(ah1[kk], bh, acc1, 0, 0, 0); \
      acc1 = __builtin_amdgcn_mfma_f32_16x16x32_bf16(ah1[kk], bl, acc1, 0, 0, 0); \
      acc1 = __builtin_amdgcn_mfma_f32_16x16x32_bf16(al1[kk], bh, acc1, 0, 0, 0); \
    }                                                                          \
    _Pragma("unroll")                                                          \
    for (int j = 0; j < 4; ++j) {                                              \
      qf0[OH][j] = fmaf(hc[j], acc0[j], qf0[OH][j]);                           \
      qf1[OH][j] = fmaf(hc[4 + j], acc1[j], qf1[OH][j]);                       \
    }                                                                          \
  }

  for (int t2 = 0; t2 < 128; ++t2) {
    const int ct0 = t2 * 2;
    // h values for hidx = t2 (shared by both halves); 8 rows per lane
    float hc[8];
    {
      const float* hp = Hh + (size_t)(row0 + wave * 32 + kg * 4) * 128 + t2;
#pragma unroll
      for (int j = 0; j < 4; ++j) {
        hc[j] = hp[(size_t)j * 128];
        hc[4 + j] = hp[(size_t)(16 + j) * 128];
      }
    }
    // issue loads for chunk ct0+1 (always < 256)
    short8_t sh1 = *(const short8_t*)(Whi + (size_t)(ct0 + 1) * 4096 + tid * 8);
    short8_t sl1 = *(const short8_t*)(Wlo + (size_t)(ct0 + 1) * 4096 + tid * 8);
    COMPUTE_HALF(0, 0)
    *(short8_t*)&Bhi[1][tid * 8] = sh1;
    *(short8_t*)&Blo[1][tid * 8] = sl1;
    __syncthreads();
    // issue loads for chunk ct0+2 (skip on last iteration)
    short8_t sh2, sl2;
    if (t2 < 127) {
      sh2 = *(const short8_t*)(Whi + (size_t)(ct0 + 2) * 4096 + tid * 8);
      sl2 = *(const short8_t*)(Wlo + (size_t)(ct0 + 2) * 4096 + tid * 8);
    }
    COMPUTE_HALF(1, 1)
    if (t2 < 127) {
      *(short8_t*)&Bhi[0][tid * 8] = sh2;
      *(short8_t*)&Blo[0][tid * 8] = sl2;
    }
    __syncthreads();
  }
#undef COMPUTE_HALF

  // ---- epilogue: q = qf + biasq, rows disjoint per wave -> direct store ----
#pragma unroll
  for (int j = 0; j < 4; ++j) {
    const size_t r0 = (size_t)(row0 + wave * 32 + kg * 4 + j) * 32;
    const size_t r1 = (size_t)(row0 + wave * 32 + 16 + kg * 4 + j) * 32;
    Qout[r0 + cl] = qf0[0][j] + Bq[r0 + cl];
    Qout[r0 + 16 + cl] = qf0[1][j] + Bq[r0 + 16 + cl];
    Qout[r1 + cl] = qf1[0][j] + Bq[r1 + cl];
    Qout[r1 + 16 + cl] = qf1[1][j] + Bq[r1 + 16 + cl];
  }
}

extern "C" void kernel_launch(void* const* d_in, const int* in_sizes, int n_in,
                              void* d_out, int out_size, void* d_ws, size_t ws_size,
                              hipStream_t stream) {
  const float* inputs   = (const float*)d_in[0];
  const float* hidden   = (const float*)d_in[1];
  const float* fc1_w    = (const float*)d_in[2];
  const float* fc1_b    = (const float*)d_in[3];
  const float* gru_wi   = (const float*)d_in[4];
  const float* gru_wh   = (const float*)d_in[5];
  const float* gru_bi   = (const float*)d_in[6];
  const float* gru_bh   = (const float*)d_in[7];
  const float* attn_q_w = (const float*)d_in[8];
  const float* attn_k_w = (const float*)d_in[9];
  const float* se1_w    = (const float*)d_in[10];
  const float* se1_b    = (const float*)d_in[11];
  const float* se2_w    = (const float*)d_in[12];
  const float* se2_b    = (const float*)d_in[13];
  const float* ga_w     = (const float*)d_in[14];
  const float* ga_b     = (const float*)d_in[15];
  const float* gemb     = (const float*)d_in[16];
  const float* gd1_w    = (const float*)d_in[17];
  const float* gd1_b    = (const float*)d_in[18];
  const float* gd2_w    = (const float*)d_in[19];
  const float* gd2_b    = (const float*)d_in[20];
  const float* hb_w     = (const float*)d_in[21];
  const float* hb_b     = (const float*)d_in[22];
  const float* hw_w     = (const float*)d_in[23];
  const float* hw_b     = (const float*)d_in[24];

  float* out = (float*)d_out;
  float* q_out     = out;              // [R,32]
  float* h_out     = out + 2097152;    // [R,128]
  float* gs_out    = out + 10485760;   // [R,256]
  float* probs_out = out + 27262976;   // [R,3]
  float* attn_out  = out + 27459584;   // [B,32,32]

  // workspace (floats). Region A = ws[0 .. 16.7M) (64MB), Region B = ws[16.7M .. 33.5M).
  float* ws = (float*)d_ws;
  float* x1 = ws;              // [R,128] (A; dead after GRU)
  float* qp = ws;              // [R,128] (A)
  float* kp = ws + 8388608;    // [R,128] (A)
  float* si = ws + 16777216;   // [R,34]  (B; dead after se1)
  float* s1 = ws;              // [R,256] (A; dead after se2)
  float* t  = ws;              // [R,256] (A; dead after gd1)
  float* g1 = ws + 16777216;   // [R,256] (B; dead after gd2)
  // After gd1, region A is dead -> reuse for hyper-q scratch:
  float* biasq = ws;                                        // [R,32] = 8 MB (bytes 0-8M)
  short* Whi = (short*)((char*)d_ws + (size_t)8 * 1024 * 1024);   // 2 MB (bytes 8-10M)
  short* Wlo = (short*)((char*)d_ws + (size_t)10 * 1024 * 1024);  // 2 MB (bytes 10-12M)

  dim3 blk(256);
  // 1) x1 = relu(inputs @ fc1_w + fc1_b)
  sgemm_kernel<1><<<dim3(2, 1024), blk, 0, stream>>>(inputs, fc1_w, fc1_b, x1, 65536, 128, 160);
  // 2) h = GRUCell(x1, hidden)
  gru_kernel<<<dim3(2, 1024), blk, 0, stream>>>(x1, hidden, gru_wi, gru_wh, gru_bi, gru_bh, h_out);
  // 3) q_/k_ projections
  sgemm_kernel<0><<<dim3(2, 1024), blk, 0, stream>>>(h_out, attn_q_w, nullptr, qp, 65536, 128, 128);
  sgemm_kernel<0><<<dim3(2, 1024), blk, 0, stream>>>(h_out, attn_k_w, nullptr, kp, 65536, 128, 128);
  // 4) attention -> attn_out + struct_input
  attn_kernel<<<dim3(2048), blk, 0, stream>>>(qp, kp, attn_out, si);
  // 5) s1 = relu(si @ se1_w + se1_b)
  sgemm_kernel<1><<<dim3(4, 1024), blk, 0, stream>>>(si, se1_w, se1_b, s1, 65536, 256, 34);
  // 6) struct_feat -> staged in gs_out
  sgemm_kernel<2><<<dim3(4, 1024), blk, 0, stream>>>(s1, se2_w, se2_b, gs_out, 65536, 256, 256);
  // 7) probs + t
  group_kernel<<<dim3(16384), blk, 0, stream>>>(gs_out, ga_w, ga_b, gemb, probs_out, t);
  // 8) g1 = relu(t @ gd1_w + gd1_b)   (last reader of region A)
  sgemm_kernel<1><<<dim3(4, 1024), blk, 0, stream>>>(t, gd1_w, gd1_b, g1, 65536, 256, 256);
  // 8.5) pack hw_w -> fragment-ordered bf16 hi/lo (region A now free)
  pack_w_kernel<<<dim3(4096), blk, 0, stream>>>(hw_w, Whi, Wlo);
  // 9) group_state = tanh(g1 @ gd2_w + gd2_b) -> gs_out
  sgemm_kernel<2><<<dim3(4, 1024), blk, 0, stream>>>(g1, gd2_w, gd2_b, gs_out, 65536, 256, 256);
  // 9.5) bias part of q
  biasq_kernel<<<dim3(8192), blk, 0, stream>>>(gs_out, h_out, hb_w, hb_b, hw_b, biasq);
  // 10) q via MFMA split-bf16, A-in-registers, W-through-LDS
  hyper_q_reg_kernel<<<dim3(256), dim3(512), 0, stream>>>(gs_out, h_out, Whi, Wlo, biasq, q_out);
}

// Round 4
// 912.969 us; speedup vs baseline: 8.9992x; 1.6545x over previous
//
#include <hip/hip_runtime.h>
#include <math.h>

// B=2048, A=32 -> R=65536 rows. E_IN=160, H=128, HE=256, NACT=32, G=3, TAU=1.
#define R_TOTAL 65536

typedef __attribute__((ext_vector_type(8))) short short8_t;
typedef __attribute__((ext_vector_type(4))) float f32x4_t;

__device__ __forceinline__ float sigmoidf_(float x) { return 1.f / (1.f + expf(-x)); }

__device__ __forceinline__ short f2bf(float x) {
  unsigned u = __float_as_uint(x);
  u += 0x7fff + ((u >> 16) & 1);   // round-to-nearest-even
  return (short)(u >> 16);
}
__device__ __forceinline__ float bf2f(short s) {
  return __uint_as_float(((unsigned)(unsigned short)s) << 16);
}

// Load 8 consecutive floats -> bf16 hi/lo split fragments.
__device__ __forceinline__ void load_afrag(const float* p, short8_t& h, short8_t& l) {
  float4 u0 = *(const float4*)p;
  float4 u1 = *(const float4*)(p + 4);
  float v[8] = {u0.x, u0.y, u0.z, u0.w, u1.x, u1.y, u1.z, u1.w};
#pragma unroll
  for (int i = 0; i < 8; ++i) {
    short hh = f2bf(v[i]);
    h[i] = hh;
    l[i] = f2bf(v[i] - bf2f(hh));
  }
}

// 3-MFMA split-bf16 product for two m-fragments sharing one B fragment pair.
#define TRIP(A0, A1, AH0, AL0, AH1, AL1, BH, BL)                               \
  A0 = __builtin_amdgcn_mfma_f32_16x16x32_bf16(AH0, BH, A0, 0, 0, 0);          \
  A0 = __builtin_amdgcn_mfma_f32_16x16x32_bf16(AH0, BL, A0, 0, 0, 0);          \
  A0 = __builtin_amdgcn_mfma_f32_16x16x32_bf16(AL0, BH, A0, 0, 0, 0);          \
  A1 = __builtin_amdgcn_mfma_f32_16x16x32_bf16(AH1, BH, A1, 0, 0, 0);          \
  A1 = __builtin_amdgcn_mfma_f32_16x16x32_bf16(AH1, BL, A1, 0, 0, 0);          \
  A1 = __builtin_amdgcn_mfma_f32_16x16x32_bf16(AL1, BH, A1, 0, 0, 0);

// ---------------- gather-style fragment pack: W[K,N] fp32 -> hi/lo bf16 ----------------
// packed p = ((ct*KK + kk)*64 + lane)*8 + i ; e = kk*32 + (lane>>4)*8 + i ; c = ct*16 + (lane&15)
__global__ __launch_bounds__(256) void pack_kernel(
    const float* __restrict__ W, int Ksrc, int N, int KK,
    short* __restrict__ Phi, short* __restrict__ Plo, int total) {
  int p = blockIdx.x * 256 + threadIdx.x;
  if (p >= total) return;
  int i = p & 7, lane = (p >> 3) & 63, kk = (p >> 9) % KK, ct = p / (KK * 512);
  int e = kk * 32 + (lane >> 4) * 8 + i;
  int c = ct * 16 + (lane & 15);
  float w = (e < Ksrc) ? W[(size_t)e * N + c] : 0.f;
  short hi = f2bf(w);
  Phi[p] = hi;
  Plo[p] = f2bf(w - bf2f(hi));
}

// ---------------- generic MFMA GEMM: C[R,N] = act(A[R,K(lda)] @ W + bias) ----------------
// BM=128 (4 waves x 32 rows), grid 512. A in registers (bf16 hi/lo), W streamed from L2.
// ACT: 0 none, 1 relu, 2 tanh. In-place (C==A) is safe: A fully read before stores.
template <int KK, int NCT, int ACT>
__global__ __launch_bounds__(256) void mfma_gemm_kernel(
    const float* A, int lda,
    const short* __restrict__ Whi, const short* __restrict__ Wlo,
    const float* __restrict__ bias, float* C) {
  const int tid = threadIdx.x;
  const int wave = tid >> 6, lane = tid & 63;
  const int cl = lane & 15, kg = lane >> 4;
  const int row0 = blockIdx.x * 128 + wave * 32;
  constexpr int N = NCT * 16;
  short8_t ah[2][KK], al[2][KK];
#pragma unroll
  for (int m = 0; m < 2; ++m) {
    const float* ap = A + (size_t)(row0 + m * 16 + cl) * lda;
#pragma unroll
    for (int kk = 0; kk < KK; ++kk) load_afrag(ap + kk * 32 + kg * 8, ah[m][kk], al[m][kk]);
  }
  for (int ct = 0; ct < NCT; ++ct) {
    f32x4_t a0 = (f32x4_t){0.f, 0.f, 0.f, 0.f};
    f32x4_t a1 = (f32x4_t){0.f, 0.f, 0.f, 0.f};
#pragma unroll
    for (int kk = 0; kk < KK; ++kk) {
      short8_t b_h = *(const short8_t*)(Whi + (((size_t)ct * KK + kk) * 64 + lane) * 8);
      short8_t b_l = *(const short8_t*)(Wlo + (((size_t)ct * KK + kk) * 64 + lane) * 8);
      TRIP(a0, a1, ah[0][kk], al[0][kk], ah[1][kk], al[1][kk], b_h, b_l)
    }
    int col = ct * 16 + cl;
    float bv = bias ? bias[col] : 0.f;
#pragma unroll
    for (int j = 0; j < 4; ++j) {
      float v0 = a0[j] + bv, v1 = a1[j] + bv;
      if (ACT == 1) { v0 = fmaxf(v0, 0.f); v1 = fmaxf(v1, 0.f); }
      if (ACT == 2) { v0 = tanhf(v0); v1 = tanhf(v1); }
      C[(size_t)(row0 + kg * 4 + j) * N + col] = v0;
      C[(size_t)(row0 + 16 + kg * 4 + j) * N + col] = v1;
    }
  }
}

// ---------------- MFMA GRU: h = GRUCell(x, h_in), both GEMMs + gate epilogue ----------------
// Wi/Wh packed (K=128 KK=4, N=384 NCT=24; gate r=ct, z=ct+8, n=ct+16).
__global__ __launch_bounds__(256) void gru_mfma_kernel(
    const float* __restrict__ X, const float* __restrict__ Hin,
    const short* __restrict__ WiHi, const short* __restrict__ WiLo,
    const short* __restrict__ WhHi, const short* __restrict__ WhLo,
    const float* __restrict__ gbi, const float* __restrict__ gbh,
    float* __restrict__ Hout) {
  const int tid = threadIdx.x;
  const int wave = tid >> 6, lane = tid & 63;
  const int cl = lane & 15, kg = lane >> 4;
  const int row0 = blockIdx.x * 128 + wave * 32;
  short8_t xh[2][4], xl[2][4], hh[2][4], hl[2][4];
#pragma unroll
  for (int m = 0; m < 2; ++m) {
    const float* xp = X + (size_t)(row0 + m * 16 + cl) * 128;
    const float* hp = Hin + (size_t)(row0 + m * 16 + cl) * 128;
#pragma unroll
    for (int kk = 0; kk < 4; ++kk) {
      load_afrag(xp + kk * 32 + kg * 8, xh[m][kk], xl[m][kk]);
      load_afrag(hp + kk * 32 + kg * 8, hh[m][kk], hl[m][kk]);
    }
  }
#define GLOAD(P, CT) *(const short8_t*)((P) + (((size_t)(CT) * 4 + kk) * 64 + lane) * 8)
  for (int ct = 0; ct < 8; ++ct) {
    f32x4_t aXr[2], aXz[2], aXn[2], aHr[2], aHz[2], aHn[2];
#pragma unroll
    for (int m = 0; m < 2; ++m) {
      aXr[m] = (f32x4_t){0.f, 0.f, 0.f, 0.f};
      aXz[m] = (f32x4_t){0.f, 0.f, 0.f, 0.f};
      aXn[m] = (f32x4_t){0.f, 0.f, 0.f, 0.f};
      aHr[m] = (f32x4_t){0.f, 0.f, 0.f, 0.f};
      aHz[m] = (f32x4_t){0.f, 0.f, 0.f, 0.f};
      aHn[m] = (f32x4_t){0.f, 0.f, 0.f, 0.f};
    }
#pragma unroll
    for (int kk = 0; kk < 4; ++kk) {
      short8_t b_h, b_l;
      b_h = GLOAD(WiHi, ct);      b_l = GLOAD(WiLo, ct);
      TRIP(aXr[0], aXr[1], xh[0][kk], xl[0][kk], xh[1][kk], xl[1][kk], b_h, b_l)
      b_h = GLOAD(WiHi, ct + 8);  b_l = GLOAD(WiLo, ct + 8);
      TRIP(aXz[0], aXz[1], xh[0][kk], xl[0][kk], xh[1][kk], xl[1][kk], b_h, b_l)
      b_h = GLOAD(WiHi, ct + 16); b_l = GLOAD(WiLo, ct + 16);
      TRIP(aXn[0], aXn[1], xh[0][kk], xl[0][kk], xh[1][kk], xl[1][kk], b_h, b_l)
      b_h = GLOAD(WhHi, ct);      b_l = GLOAD(WhLo, ct);
      TRIP(aHr[0], aHr[1], hh[0][kk], hl[0][kk], hh[1][kk], hl[1][kk], b_h, b_l)
      b_h = GLOAD(WhHi, ct + 8);  b_l = GLOAD(WhLo, ct + 8);
      TRIP(aHz[0], aHz[1], hh[0][kk], hl[0][kk], hh[1][kk], hl[1][kk], b_h, b_l)
      b_h = GLOAD(WhHi, ct + 16); b_l = GLOAD(WhLo, ct + 16);
      TRIP(aHn[0], aHn[1], hh[0][kk], hl[0][kk], hh[1][kk], hl[1][kk], b_h, b_l)
    }
    int col = ct * 16 + cl;
    float bir = gbi[col], biz = gbi[128 + col], bin = gbi[256 + col];
    float bhr = gbh[col], bhz = gbh[128 + col], bhn = gbh[256 + col];
#pragma unroll
    for (int m = 0; m < 2; ++m)
#pragma unroll
      for (int j = 0; j < 4; ++j) {
        int row = row0 + m * 16 + kg * 4 + j;
        float rg = sigmoidf_(aXr[m][j] + aHr[m][j] + bir + bhr);
        float zg = sigmoidf_(aXz[m][j] + aHz[m][j] + biz + bhz);
        float ng = tanhf(aXn[m][j] + bin + rg * (aHn[m][j] + bhn));
        float hv = Hin[(size_t)row * 128 + col];
        Hout[(size_t)row * 128 + col] = (1.f - zg) * ng + zg * hv;
      }
  }
#undef GLOAD
}

// ---------------- attention block (reads combined qk [R,256], writes padded si [R,64]) --------
__global__ __launch_bounds__(256) void attn_kernel(
    const float* __restrict__ QK, float* __restrict__ attn_out, float* __restrict__ si) {
  __shared__ float qs[32][129];
  __shared__ float ks[32][129];
  __shared__ float p[32][33];
  __shared__ float a2[32][33];
  const int b = blockIdx.x;
  const int tid = threadIdx.x;
  const float* qb = QK + (size_t)b * 8192;
  for (int i = tid; i < 4096; i += 256) {
    int r = i >> 7, e = i & 127;
    qs[r][e] = qb[r * 256 + e];
    ks[r][e] = qb[r * 256 + 128 + e];
  }
  __syncthreads();
  const float scale = 0.088388347648318447f;  // 1/sqrt(128)
#pragma unroll
  for (int tI = 0; tI < 4; ++tI) {
    int t = tid + tI * 256;
    int i = t >> 5, j = t & 31;
    float s = 0.f;
    for (int e = 0; e < 128; ++e) s = fmaf(qs[i][e], ks[j][e], s);
    p[i][j] = (i == j) ? -1e9f : s * scale;
  }
  __syncthreads();
  if (tid < 32) {
    const int i = tid;
    float m = -1e30f;
    for (int j = 0; j < 32; ++j) m = fmaxf(m, p[i][j]);
    float sum = 0.f;
    for (int j = 0; j < 32; ++j) {
      float e = expf(p[i][j] - m);
      p[i][j] = e;
      sum += e;
    }
    float inv = 1.f / sum;
    for (int j = 0; j < 32; ++j) p[i][j] *= inv;
  }
  __syncthreads();
#pragma unroll
  for (int tI = 0; tI < 4; ++tI) {
    int t = tid + tI * 256;
    int i = t >> 5, j = t & 31;
    float v = (i == j) ? 0.f : 0.5f * (p[i][j] + p[j][i]);
    a2[i][j] = v;
    attn_out[(size_t)b * 1024 + t] = v;
  }
  __syncthreads();
  if (tid < 32) {
    const int i = tid;
    float d = 0.f, en = 0.f;
    for (int j = 0; j < 32; ++j) {
      float v = a2[i][j];
      d += v;
      float c = fmaxf(v, 1e-8f);
      en -= c * logf(c);
    }
    float* srow = si + ((size_t)b * 32 + i) * 64;
    for (int j = 0; j < 32; ++j) srow[j] = a2[i][j];
    srow[32] = d;
    srow[33] = en;
    for (int j = 34; j < 64; ++j) srow[j] = 0.f;
  }
}

// ---------------- group assign ----------------
__global__ __launch_bounds__(256) void group_kernel(
    const float* __restrict__ sf, const float* __restrict__ ga_w,
    const float* __restrict__ ga_b, const float* __restrict__ gemb,
    float* __restrict__ probs, float* __restrict__ tout) {
  const size_t r = (size_t)blockIdx.x * 4 + (threadIdx.x >> 6);
  const int lane = threadIdx.x & 63;
  const int e = lane * 4;
  const float4 s4 = *(const float4*)(sf + r * 256 + e);
  float lg[3];
#pragma unroll
  for (int g = 0; g < 3; ++g) {
    lg[g] = s4.x * ga_w[(e + 0) * 3 + g] + s4.y * ga_w[(e + 1) * 3 + g] +
            s4.z * ga_w[(e + 2) * 3 + g] + s4.w * ga_w[(e + 3) * 3 + g];
  }
#pragma unroll
  for (int off = 32; off; off >>= 1) {
#pragma unroll
    for (int g = 0; g < 3; ++g) lg[g] += __shfl_xor(lg[g], off, 64);
  }
#pragma unroll
  for (int g = 0; g < 3; ++g) lg[g] += ga_b[g];
  float m = fmaxf(lg[0], fmaxf(lg[1], lg[2]));
  float e0 = expf(lg[0] - m), e1 = expf(lg[1] - m), e2 = expf(lg[2] - m);
  float inv = 1.f / (e0 + e1 + e2);
  float p0 = e0 * inv, p1 = e1 * inv, p2 = e2 * inv;
  if (lane == 0) probs[r * 3 + 0] = p0;
  if (lane == 1) probs[r * 3 + 1] = p1;
  if (lane == 2) probs[r * 3 + 2] = p2;
  float4 t4;
  t4.x = s4.x + p0 * gemb[e + 0] + p1 * gemb[256 + e + 0] + p2 * gemb[512 + e + 0];
  t4.y = s4.y + p0 * gemb[e + 1] + p1 * gemb[256 + e + 1] + p2 * gemb[512 + e + 1];
  t4.z = s4.z + p0 * gemb[e + 2] + p1 * gemb[256 + e + 2] + p2 * gemb[512 + e + 2];
  t4.w = s4.w + p0 * gemb[e + 3] + p1 * gemb[256 + e + 3] + p2 * gemb[512 + e + 3];
  *(float4*)(tout + r * 256 + e) = t4;
}

// ---------------- MFMA hypernet q: A in registers, W through LDS dbuf, bias folded --------
// W packed has 258 chunks: 0..255 = hw_w, 256..257 = hb_w. hw_b added to P pre-contraction,
// hb_b at store. 256 blocks x 512 threads (8 waves), wave owns 32 rows.
__global__ __launch_bounds__(512, 2) void hyper_q_reg_kernel(
    const float* __restrict__ GS, const float* __restrict__ Hh,
    const short* __restrict__ Whi, const short* __restrict__ Wlo,
    const float* __restrict__ hwb, const float* __restrict__ hbb,
    float* __restrict__ Qout) {
  __shared__ short Bhi[2][4096];   // 16 KB
  __shared__ short Blo[2][4096];   // 16 KB
  const int tid = threadIdx.x;
  const int wave = tid >> 6, lane = tid & 63;
  const int cl = lane & 15, kg = lane >> 4;
  const int row0 = blockIdx.x * 256;

  // ---- A (gs) -> registers as bf16 hi/lo fragments ----
  short8_t ah0[8], al0[8], ah1[8], al1[8];
  {
    const float* a0p = GS + (size_t)(row0 + wave * 32 + cl) * 256;
    const float* a1p = a0p + 16 * 256;
#pragma unroll
    for (int kk = 0; kk < 8; ++kk) {
      load_afrag(a0p + kk * 32 + kg * 8, ah0[kk], al0[kk]);
      load_afrag(a1p + kk * 32 + kg * 8, ah1[kk], al1[kk]);
    }
  }

  // ---- prologue: stage chunk 0 into buf 0 ----
  {
    short8_t vh = *(const short8_t*)(Whi + tid * 8);
    short8_t vl = *(const short8_t*)(Wlo + tid * 8);
    *(short8_t*)&Bhi[0][tid * 8] = vh;
    *(short8_t*)&Blo[0][tid * 8] = vl;
  }
  __syncthreads();

  float qf0[2][4] = {};  // [oh][j] for m=0
  float qf1[2][4] = {};  // [oh][j] for m=1

#define COMPUTE_HALF(BUF, OH, WB)                                              \
  {                                                                            \
    f32x4_t acc0 = (f32x4_t){0.f, 0.f, 0.f, 0.f};                              \
    f32x4_t acc1 = (f32x4_t){0.f, 0.f, 0.f, 0.f};                              \
    _Pragma("unroll")                                                          \
    for (int kk = 0; kk < 8; ++kk) {                                           \
      short8_t b_h = *(const short8_t*)&Bhi[BUF][(kk * 64 + lane) * 8];        \
      short8_t b_l = *(const short8_t*)&Blo[BUF][(kk * 64 + lane) * 8];        \
      TRIP(acc0, acc1, ah0[kk], al0[kk], ah1[kk], al1[kk], b_h, b_l)           \
    }                                                                          \
    _Pragma("unroll")                                                          \
    for (int j = 0; j < 4; ++j) {                                              \
      qf0[OH][j] = fmaf(hc[j], acc0[j] + (WB), qf0[OH][j]);                    \
      qf1[OH][j] = fmaf(hc[4 + j], acc1[j] + (WB), qf1[OH][j]);                \
    }                                                                          \
  }

  for (int t2 = 0; t2 < 128; ++t2) {
    const int ct0 = t2 * 2;
    float hc[8];
    {
      const float* hp = Hh + (size_t)(row0 + wave * 32 + kg * 4) * 128 + t2;
#pragma unroll
      for (int j = 0; j < 4; ++j) {
        hc[j] = hp[(size_t)j * 128];
        hc[4 + j] = hp[(size_t)(16 + j) * 128];
      }
    }
    float wb0 = hwb[ct0 * 16 + cl];
    float wb1 = hwb[(ct0 + 1) * 16 + cl];
    // issue loads for chunk ct0+1 (always < 256)
    short8_t sh1 = *(const short8_t*)(Whi + (size_t)(ct0 + 1) * 4096 + tid * 8);
    short8_t sl1 = *(const short8_t*)(Wlo + (size_t)(ct0 + 1) * 4096 + tid * 8);
    COMPUTE_HALF(0, 0, wb0)
    *(short8_t*)&Bhi[1][tid * 8] = sh1;
    *(short8_t*)&Blo[1][tid * 8] = sl1;
    __syncthreads();
    short8_t sh2, sl2;
    if (t2 < 127) {
      sh2 = *(const short8_t*)(Whi + (size_t)(ct0 + 2) * 4096 + tid * 8);
      sl2 = *(const short8_t*)(Wlo + (size_t)(ct0 + 2) * 4096 + tid * 8);
    }
    COMPUTE_HALF(1, 1, wb1)
    if (t2 < 127) {
      *(short8_t*)&Bhi[0][tid * 8] = sh2;
      *(short8_t*)&Blo[0][tid * 8] = sl2;
    }
    __syncthreads();
  }
#undef COMPUTE_HALF

  // ---- fc2_b part: gs @ hb_w via packed chunks 256/257 (contract with 1) ----
#pragma unroll
  for (int oh = 0; oh < 2; ++oh) {
    f32x4_t b0 = (f32x4_t){0.f, 0.f, 0.f, 0.f};
    f32x4_t b1 = (f32x4_t){0.f, 0.f, 0.f, 0.f};
#pragma unroll
    for (int kk = 0; kk < 8; ++kk) {
      short8_t b_h = *(const short8_t*)(Whi + (((size_t)(256 + oh) * 8 + kk) * 64 + lane) * 8);
      short8_t b_l = *(const short8_t*)(Wlo + (((size_t)(256 + oh) * 8 + kk) * 64 + lane) * 8);
      TRIP(b0, b1, ah0[kk], al0[kk], ah1[kk], al1[kk], b_h, b_l)
    }
#pragma unroll
    for (int j = 0; j < 4; ++j) {
      qf0[oh][j] += b0[j];
      qf1[oh][j] += b1[j];
    }
  }

  // ---- epilogue: q = qf + hb_b ----
  float hbb0 = hbb[cl], hbb1 = hbb[16 + cl];
#pragma unroll
  for (int j = 0; j < 4; ++j) {
    const size_t r0 = (size_t)(row0 + wave * 32 + kg * 4 + j) * 32;
    const size_t r1 = (size_t)(row0 + wave * 32 + 16 + kg * 4 + j) * 32;
    Qout[r0 + cl] = qf0[0][j] + hbb0;
    Qout[r0 + 16 + cl] = qf0[1][j] + hbb1;
    Qout[r1 + cl] = qf1[0][j] + hbb0;
    Qout[r1 + 16 + cl] = qf1[1][j] + hbb1;
  }
}

extern "C" void kernel_launch(void* const* d_in, const int* in_sizes, int n_in,
                              void* d_out, int out_size, void* d_ws, size_t ws_size,
                              hipStream_t stream) {
  const float* inputs   = (const float*)d_in[0];
  const float* hidden   = (const float*)d_in[1];
  const float* fc1_w    = (const float*)d_in[2];
  const float* fc1_b    = (const float*)d_in[3];
  const float* gru_wi   = (const float*)d_in[4];
  const float* gru_wh   = (const float*)d_in[5];
  const float* gru_bi   = (const float*)d_in[6];
  const float* gru_bh   = (const float*)d_in[7];
  const float* attn_q_w = (const float*)d_in[8];
  const float* attn_k_w = (const float*)d_in[9];
  const float* se1_w    = (const float*)d_in[10];
  const float* se1_b    = (const float*)d_in[11];
  const float* se2_w    = (const float*)d_in[12];
  const float* se2_b    = (const float*)d_in[13];
  const float* ga_w     = (const float*)d_in[14];
  const float* ga_b     = (const float*)d_in[15];
  const float* gemb     = (const float*)d_in[16];
  const float* gd1_w    = (const float*)d_in[17];
  const float* gd1_b    = (const float*)d_in[18];
  const float* gd2_w    = (const float*)d_in[19];
  const float* gd2_b    = (const float*)d_in[20];
  const float* hb_w     = (const float*)d_in[21];
  const float* hb_b     = (const float*)d_in[22];
  const float* hw_w     = (const float*)d_in[23];
  const float* hw_b     = (const float*)d_in[24];

  float* out = (float*)d_out;
  float* q_out     = out;              // [R,32]
  float* h_out     = out + 2097152;    // [R,128]
  float* gs_out    = out + 10485760;   // [R,256]
  float* probs_out = out + 27262976;   // [R,3]
  float* attn_out  = out + 27459584;   // [B,32,32]

  // workspace layout:
  //   region0 [0, 64MiB):  qk [R,256] -> s1 [R,256] -> t [R,256] (gd1 in-place)
  //   si      [64, 80MiB): [R,64] padded struct_input
  //   x1      [80, 112MiB): [R,128]
  //   packs   [112MiB, ~117.7MiB)
  float* ws = (float*)d_ws;
  float* qk = ws;                      // region0
  float* s1 = ws;                      // region0 (qk dead after attn)
  float* t  = ws;                      // region0 (s1 dead after se2)
  float* si = ws + 16777216;
  float* x1 = ws + 16777216 + 4194304;
  short* P  = (short*)((char*)d_ws + (size_t)112 * 1024 * 1024);

  // pack offsets (shorts)
  const size_t o_hw_hi  = 0;                         // 1048576 + 8192 (hb chunks)
  const size_t o_hw_lo  = o_hw_hi + 1056768;
  const size_t o_fc1_hi = o_hw_lo + 1056768;
  const size_t o_fc1_lo = o_fc1_hi + 20480;
  const size_t o_wi_hi  = o_fc1_lo + 20480;
  const size_t o_wi_lo  = o_wi_hi + 49152;
  const size_t o_wh_hi  = o_wi_lo + 49152;
  const size_t o_wh_lo  = o_wh_hi + 49152;
  const size_t o_qk_hi  = o_wh_lo + 49152;
  const size_t o_qk_lo  = o_qk_hi + 32768;
  const size_t o_se1_hi = o_qk_lo + 32768;
  const size_t o_se1_lo = o_se1_hi + 16384;
  const size_t o_se2_hi = o_se1_lo + 16384;
  const size_t o_se2_lo = o_se2_hi + 65536;
  const size_t o_gd1_hi = o_se2_lo + 65536;
  const size_t o_gd1_lo = o_gd1_hi + 65536;
  const size_t o_gd2_hi = o_gd1_lo + 65536;
  const size_t o_gd2_lo = o_gd2_hi + 65536;

  dim3 blk(256);
  // ---- weight packs (independent of activations; run first) ----
  pack_kernel<<<4096, blk, 0, stream>>>(hw_w, 256, 4096, 8, P + o_hw_hi, P + o_hw_lo, 1048576);
  pack_kernel<<<32, blk, 0, stream>>>(hb_w, 256, 32, 8, P + o_hw_hi + 1048576, P + o_hw_lo + 1048576, 8192);
  pack_kernel<<<80, blk, 0, stream>>>(fc1_w, 160, 128, 5, P + o_fc1_hi, P + o_fc1_lo, 20480);
  pack_kernel<<<192, blk, 0, stream>>>(gru_wi, 128, 384, 4, P + o_wi_hi, P + o_wi_lo, 49152);
  pack_kernel<<<192, blk, 0, stream>>>(gru_wh, 128, 384, 4, P + o_wh_hi, P + o_wh_lo, 49152);
  pack_kernel<<<64, blk, 0, stream>>>(attn_q_w, 128, 128, 4, P + o_qk_hi, P + o_qk_lo, 16384);
  pack_kernel<<<64, blk, 0, stream>>>(attn_k_w, 128, 128, 4, P + o_qk_hi + 16384, P + o_qk_lo + 16384, 16384);
  pack_kernel<<<64, blk, 0, stream>>>(se1_w, 34, 256, 2, P + o_se1_hi, P + o_se1_lo, 16384);
  pack_kernel<<<256, blk, 0, stream>>>(se2_w, 256, 256, 8, P + o_se2_hi, P + o_se2_lo, 65536);
  pack_kernel<<<256, blk, 0, stream>>>(gd1_w, 256, 256, 8, P + o_gd1_hi, P + o_gd1_lo, 65536);
  pack_kernel<<<256, blk, 0, stream>>>(gd2_w, 256, 256, 8, P + o_gd2_hi, P + o_gd2_lo, 65536);

  // 1) x1 = relu(inputs @ fc1_w + fc1_b)            K=160 N=128
  mfma_gemm_kernel<5, 8, 1><<<512, blk, 0, stream>>>(inputs, 160, P + o_fc1_hi, P + o_fc1_lo, fc1_b, x1);
  // 2) h = GRUCell(x1, hidden)
  gru_mfma_kernel<<<512, blk, 0, stream>>>(x1, hidden, P + o_wi_hi, P + o_wi_lo, P + o_wh_hi, P + o_wh_lo,
                                           gru_bi, gru_bh, h_out);
  // 3) qk = h @ [attn_q_w | attn_k_w]               K=128 N=256
  mfma_gemm_kernel<4, 16, 0><<<512, blk, 0, stream>>>(h_out, 128, P + o_qk_hi, P + o_qk_lo, nullptr, qk);
  // 4) attention -> attn_out + padded struct_input
  attn_kernel<<<2048, blk, 0, stream>>>(qk, attn_out, si);
  // 5) s1 = relu(si @ se1_w + se1_b)                K=64(pad) N=256
  mfma_gemm_kernel<2, 16, 1><<<512, blk, 0, stream>>>(si, 64, P + o_se1_hi, P + o_se1_lo, se1_b, s1);
  // 6) struct_feat = tanh(s1 @ se2_w + se2_b) -> staged in gs_out
  mfma_gemm_kernel<8, 16, 2><<<512, blk, 0, stream>>>(s1, 256, P + o_se2_hi, P + o_se2_lo, se2_b, gs_out);
  // 7) probs + t = sf + probs@group_emb
  group_kernel<<<16384, blk, 0, stream>>>(gs_out, ga_w, ga_b, gemb, probs_out, t);
  // 8) g1 = relu(t @ gd1_w + gd1_b)  (in-place: rows fully loaded to regs before stores)
  mfma_gemm_kernel<8, 16, 1><<<512, blk, 0, stream>>>(t, 256, P + o_gd1_hi, P + o_gd1_lo, gd1_b, t);
  // 9) group_state = tanh(g1 @ gd2_w + gd2_b) -> gs_out
  mfma_gemm_kernel<8, 16, 2><<<512, blk, 0, stream>>>(t, 256, P + o_gd2_hi, P + o_gd2_lo, gd2_b, gs_out);
  // 10) q via MFMA split-bf16, biases folded
  hyper_q_reg_kernel<<<dim3(256), dim3(512), 0, stream>>>(gs_out, h_out, P + o_hw_hi, P + o_hw_lo,
                                                          hw_b, hb_b, q_out);
}

// Round 5
// 617.240 us; speedup vs baseline: 13.3108x; 1.4791x over previous
//
#include <hip/hip_runtime.h>
#include <math.h>

// B=2048, A=32 -> R=65536 rows. E_IN=160, H=128, HE=256, NACT=32, G=3, TAU=1.
#define R_TOTAL 65536

typedef __attribute__((ext_vector_type(8))) short short8_t;
typedef __attribute__((ext_vector_type(4))) float f32x4_t;

__device__ __forceinline__ float sigmoidf_(float x) { return 1.f / (1.f + expf(-x)); }

__device__ __forceinline__ short f2bf(float x) {
  unsigned u = __float_as_uint(x);
  u += 0x7fff + ((u >> 16) & 1);   // round-to-nearest-even
  return (short)(u >> 16);
}

// Load 8 consecutive floats -> bf16 fragment (RNE).
__device__ __forceinline__ void load_afrag(const float* p, short8_t& h) {
  float4 u0 = *(const float4*)p;
  float4 u1 = *(const float4*)(p + 4);
  float v[8] = {u0.x, u0.y, u0.z, u0.w, u1.x, u1.y, u1.z, u1.w};
#pragma unroll
  for (int i = 0; i < 8; ++i) h[i] = f2bf(v[i]);
}

#define MFMA(ACC, A, B) ACC = __builtin_amdgcn_mfma_f32_16x16x32_bf16(A, B, ACC, 0, 0, 0)

// ---------------- fused fragment pack: all weights in one launch ----------------
// packed p = ((ct*KK + kk)*64 + lane)*8 + i ; e = kk*32 + (lane>>4)*8 + i ; c = ct*16 + (lane&15)
struct PackSeg {
  const float* W;
  int Ksrc, N, KK, blk0, nblk;
  size_t off;
};
struct PackArgs { PackSeg s[11]; };

__global__ __launch_bounds__(256) void pack_all_kernel(PackArgs a, short* __restrict__ P) {
  const int b = blockIdx.x;
  PackSeg seg = a.s[0];
#pragma unroll
  for (int i = 1; i < 11; ++i)
    if (b >= a.s[i].blk0) seg = a.s[i];
  int p = (b - seg.blk0) * 256 + threadIdx.x;
  int i = p & 7, lane = (p >> 3) & 63, kk = (p >> 9) % seg.KK, ct = p / (seg.KK * 512);
  int e = kk * 32 + (lane >> 4) * 8 + i;
  int c = ct * 16 + (lane & 15);
  float w = (e < seg.Ksrc) ? seg.W[(size_t)e * seg.N + c] : 0.f;
  P[seg.off + p] = f2bf(w);
}

// ---------------- generic MFMA GEMM: C[R,N] = act(A[R,K(lda)] @ W + bias) ----------------
// BM=128 (4 waves x 32 rows), grid 512. A in registers (bf16), W streamed from L2.
// ACT: 0 none, 1 relu, 2 tanh. In-place (C==A) is safe: A fully read before stores.
template <int KK, int NCT, int ACT>
__global__ __launch_bounds__(256) void mfma_gemm_kernel(
    const float* A, int lda, const short* __restrict__ Wp,
    const float* __restrict__ bias, float* C) {
  const int tid = threadIdx.x;
  const int wave = tid >> 6, lane = tid & 63;
  const int cl = lane & 15, kg = lane >> 4;
  const int row0 = blockIdx.x * 128 + wave * 32;
  constexpr int N = NCT * 16;
  short8_t ah[2][KK];
#pragma unroll
  for (int m = 0; m < 2; ++m) {
    const float* ap = A + (size_t)(row0 + m * 16 + cl) * lda;
#pragma unroll
    for (int kk = 0; kk < KK; ++kk) load_afrag(ap + kk * 32 + kg * 8, ah[m][kk]);
  }
  for (int ct = 0; ct < NCT; ++ct) {
    f32x4_t a0 = (f32x4_t){0.f, 0.f, 0.f, 0.f};
    f32x4_t a1 = (f32x4_t){0.f, 0.f, 0.f, 0.f};
#pragma unroll
    for (int kk = 0; kk < KK; ++kk) {
      short8_t b_h = *(const short8_t*)(Wp + (((size_t)ct * KK + kk) * 64 + lane) * 8);
      MFMA(a0, ah[0][kk], b_h);
      MFMA(a1, ah[1][kk], b_h);
    }
    int col = ct * 16 + cl;
    float bv = bias ? bias[col] : 0.f;
#pragma unroll
    for (int j = 0; j < 4; ++j) {
      float v0 = a0[j] + bv, v1 = a1[j] + bv;
      if (ACT == 1) { v0 = fmaxf(v0, 0.f); v1 = fmaxf(v1, 0.f); }
      if (ACT == 2) { v0 = tanhf(v0); v1 = tanhf(v1); }
      C[(size_t)(row0 + kg * 4 + j) * N + col] = v0;
      C[(size_t)(row0 + 16 + kg * 4 + j) * N + col] = v1;
    }
  }
}

// ---------------- MFMA GRU: h = GRUCell(x, h_in) ----------------
// Wi/Wh packed (K=128 KK=4, N=384 NCT=24; gate r=ct, z=ct+8, n=ct+16).
__global__ __launch_bounds__(256) void gru_mfma_kernel(
    const float* __restrict__ X, const float* __restrict__ Hin,
    const short* __restrict__ WiP, const short* __restrict__ WhP,
    const float* __restrict__ gbi, const float* __restrict__ gbh,
    float* __restrict__ Hout) {
  const int tid = threadIdx.x;
  const int wave = tid >> 6, lane = tid & 63;
  const int cl = lane & 15, kg = lane >> 4;
  const int row0 = blockIdx.x * 128 + wave * 32;
  short8_t xh[2][4], hh[2][4];
#pragma unroll
  for (int m = 0; m < 2; ++m) {
    const float* xp = X + (size_t)(row0 + m * 16 + cl) * 128;
    const float* hp = Hin + (size_t)(row0 + m * 16 + cl) * 128;
#pragma unroll
    for (int kk = 0; kk < 4; ++kk) {
      load_afrag(xp + kk * 32 + kg * 8, xh[m][kk]);
      load_afrag(hp + kk * 32 + kg * 8, hh[m][kk]);
    }
  }
#define GLOAD(P, CT) *(const short8_t*)((P) + (((size_t)(CT) * 4 + kk) * 64 + lane) * 8)
  for (int ct = 0; ct < 8; ++ct) {
    f32x4_t aXr[2], aXz[2], aXn[2], aHr[2], aHz[2], aHn[2];
#pragma unroll
    for (int m = 0; m < 2; ++m) {
      aXr[m] = (f32x4_t){0.f, 0.f, 0.f, 0.f};
      aXz[m] = (f32x4_t){0.f, 0.f, 0.f, 0.f};
      aXn[m] = (f32x4_t){0.f, 0.f, 0.f, 0.f};
      aHr[m] = (f32x4_t){0.f, 0.f, 0.f, 0.f};
      aHz[m] = (f32x4_t){0.f, 0.f, 0.f, 0.f};
      aHn[m] = (f32x4_t){0.f, 0.f, 0.f, 0.f};
    }
#pragma unroll
    for (int kk = 0; kk < 4; ++kk) {
      short8_t b_h;
      b_h = GLOAD(WiP, ct);      MFMA(aXr[0], xh[0][kk], b_h); MFMA(aXr[1], xh[1][kk], b_h);
      b_h = GLOAD(WiP, ct + 8);  MFMA(aXz[0], xh[0][kk], b_h); MFMA(aXz[1], xh[1][kk], b_h);
      b_h = GLOAD(WiP, ct + 16); MFMA(aXn[0], xh[0][kk], b_h); MFMA(aXn[1], xh[1][kk], b_h);
      b_h = GLOAD(WhP, ct);      MFMA(aHr[0], hh[0][kk], b_h); MFMA(aHr[1], hh[1][kk], b_h);
      b_h = GLOAD(WhP, ct + 8);  MFMA(aHz[0], hh[0][kk], b_h); MFMA(aHz[1], hh[1][kk], b_h);
      b_h = GLOAD(WhP, ct + 16); MFMA(aHn[0], hh[0][kk], b_h); MFMA(aHn[1], hh[1][kk], b_h);
    }
    int col = ct * 16 + cl;
    float bir = gbi[col], biz = gbi[128 + col], bin = gbi[256 + col];
    float bhr = gbh[col], bhz = gbh[128 + col], bhn = gbh[256 + col];
#pragma unroll
    for (int m = 0; m < 2; ++m)
#pragma unroll
      for (int j = 0; j < 4; ++j) {
        int row = row0 + m * 16 + kg * 4 + j;
        float rg = sigmoidf_(aXr[m][j] + aHr[m][j] + bir + bhr);
        float zg = sigmoidf_(aXz[m][j] + aHz[m][j] + biz + bhz);
        float ng = tanhf(aXn[m][j] + bin + rg * (aHn[m][j] + bhn));
        float hv = Hin[(size_t)row * 128 + col];
        Hout[(size_t)row * 128 + col] = (1.f - zg) * ng + zg * hv;
      }
  }
#undef GLOAD
}

// ---------------- attention block (reads combined qk [R,256], writes padded si [R,64]) --------
__global__ __launch_bounds__(256) void attn_kernel(
    const float* __restrict__ QK, float* __restrict__ attn_out, float* __restrict__ si) {
  __shared__ float qs[32][129];
  __shared__ float ks[32][129];
  __shared__ float p[32][33];
  __shared__ float a2[32][33];
  const int b = blockIdx.x;
  const int tid = threadIdx.x;
  const float* qb = QK + (size_t)b * 8192;
  for (int i = tid; i < 4096; i += 256) {
    int r = i >> 7, e = i & 127;
    qs[r][e] = qb[r * 256 + e];
    ks[r][e] = qb[r * 256 + 128 + e];
  }
  __syncthreads();
  const float scale = 0.088388347648318447f;  // 1/sqrt(128)
#pragma unroll
  for (int tI = 0; tI < 4; ++tI) {
    int t = tid + tI * 256;
    int i = t >> 5, j = t & 31;
    float s = 0.f;
    for (int e = 0; e < 128; ++e) s = fmaf(qs[i][e], ks[j][e], s);
    p[i][j] = (i == j) ? -1e9f : s * scale;
  }
  __syncthreads();
  if (tid < 32) {
    const int i = tid;
    float m = -1e30f;
    for (int j = 0; j < 32; ++j) m = fmaxf(m, p[i][j]);
    float sum = 0.f;
    for (int j = 0; j < 32; ++j) {
      float e = expf(p[i][j] - m);
      p[i][j] = e;
      sum += e;
    }
    float inv = 1.f / sum;
    for (int j = 0; j < 32; ++j) p[i][j] *= inv;
  }
  __syncthreads();
#pragma unroll
  for (int tI = 0; tI < 4; ++tI) {
    int t = tid + tI * 256;
    int i = t >> 5, j = t & 31;
    float v = (i == j) ? 0.f : 0.5f * (p[i][j] + p[j][i]);
    a2[i][j] = v;
    attn_out[(size_t)b * 1024 + t] = v;
  }
  __syncthreads();
  if (tid < 32) {
    const int i = tid;
    float d = 0.f, en = 0.f;
    for (int j = 0; j < 32; ++j) {
      float v = a2[i][j];
      d += v;
      float c = fmaxf(v, 1e-8f);
      en -= c * logf(c);
    }
    float* srow = si + ((size_t)b * 32 + i) * 64;
    for (int j = 0; j < 32; ++j) srow[j] = a2[i][j];
    srow[32] = d;
    srow[33] = en;
    for (int j = 34; j < 64; ++j) srow[j] = 0.f;
  }
}

// ---------------- group assign ----------------
__global__ __launch_bounds__(256) void group_kernel(
    const float* __restrict__ sf, const float* __restrict__ ga_w,
    const float* __restrict__ ga_b, const float* __restrict__ gemb,
    float* __restrict__ probs, float* __restrict__ tout) {
  const size_t r = (size_t)blockIdx.x * 4 + (threadIdx.x >> 6);
  const int lane = threadIdx.x & 63;
  const int e = lane * 4;
  const float4 s4 = *(const float4*)(sf + r * 256 + e);
  float lg[3];
#pragma unroll
  for (int g = 0; g < 3; ++g) {
    lg[g] = s4.x * ga_w[(e + 0) * 3 + g] + s4.y * ga_w[(e + 1) * 3 + g] +
            s4.z * ga_w[(e + 2) * 3 + g] + s4.w * ga_w[(e + 3) * 3 + g];
  }
#pragma unroll
  for (int off = 32; off; off >>= 1) {
#pragma unroll
    for (int g = 0; g < 3; ++g) lg[g] += __shfl_xor(lg[g], off, 64);
  }
#pragma unroll
  for (int g = 0; g < 3; ++g) lg[g] += ga_b[g];
  float m = fmaxf(lg[0], fmaxf(lg[1], lg[2]));
  float e0 = expf(lg[0] - m), e1 = expf(lg[1] - m), e2 = expf(lg[2] - m);
  float inv = 1.f / (e0 + e1 + e2);
  float p0 = e0 * inv, p1 = e1 * inv, p2 = e2 * inv;
  if (lane == 0) probs[r * 3 + 0] = p0;
  if (lane == 1) probs[r * 3 + 1] = p1;
  if (lane == 2) probs[r * 3 + 2] = p2;
  float4 t4;
  t4.x = s4.x + p0 * gemb[e + 0] + p1 * gemb[256 + e + 0] + p2 * gemb[512 + e + 0];
  t4.y = s4.y + p0 * gemb[e + 1] + p1 * gemb[256 + e + 1] + p2 * gemb[512 + e + 1];
  t4.z = s4.z + p0 * gemb[e + 2] + p1 * gemb[256 + e + 2] + p2 * gemb[512 + e + 2];
  t4.w = s4.w + p0 * gemb[e + 3] + p1 * gemb[256 + e + 3] + p2 * gemb[512 + e + 3];
  *(float4*)(tout + r * 256 + e) = t4;
}

// ---------------- MFMA hypernet q: pure bf16, 64 rows/wave, W through LDS dbuf ------------
// W packed: chunks 0..255 = hw_w, 256..257 = hb_w. hw_b folded pre-contraction, hb_b at store.
// 256 blocks x 256 threads (4 waves); wave owns 64 rows (4 m-frags, A-hi in registers).
__global__ __launch_bounds__(256, 2) void hyper_q_hi_kernel(
    const float* __restrict__ GS, const float* __restrict__ Hh,
    const short* __restrict__ Wp, const float* __restrict__ hwb,
    const float* __restrict__ hbb, float* __restrict__ Qout) {
  __shared__ short Bh[2][4096];   // 16 KB double buffer (one 16-col chunk each)
  const int tid = threadIdx.x;
  const int wave = tid >> 6, lane = tid & 63;
  const int cl = lane & 15, kg = lane >> 4;
  const int row0 = blockIdx.x * 256;
  const int wrow = row0 + wave * 64;

  // ---- A (gs) -> registers as bf16 fragments: 4 m-frags x 8 kk ----
  short8_t ah[4][8];
#pragma unroll
  for (int m = 0; m < 4; ++m) {
    const float* ap = GS + (size_t)(wrow + m * 16 + cl) * 256;
#pragma unroll
    for (int kk = 0; kk < 8; ++kk) load_afrag(ap + kk * 32 + kg * 8, ah[m][kk]);
  }

  // ---- prologue: stage chunk 0 into buf 0 (4096 shorts, 16 per thread) ----
  {
    short8_t v0 = *(const short8_t*)(Wp + tid * 16);
    short8_t v1 = *(const short8_t*)(Wp + tid * 16 + 8);
    *(short8_t*)&Bh[0][tid * 16] = v0;
    *(short8_t*)&Bh[0][tid * 16 + 8] = v1;
  }
  __syncthreads();

  float qf[4][2][4] = {};  // [m][oh][j]

#define COMPUTE_HALF(BUF, OH, WB)                                              \
  {                                                                            \
    f32x4_t acc[4];                                                            \
    _Pragma("unroll")                                                          \
    for (int m = 0; m < 4; ++m) acc[m] = (f32x4_t){0.f, 0.f, 0.f, 0.f};        \
    _Pragma("unroll")                                                          \
    for (int kk = 0; kk < 8; ++kk) {                                           \
      short8_t b_h = *(const short8_t*)&Bh[BUF][(kk * 64 + lane) * 8];         \
      _Pragma("unroll")                                                        \
      for (int m = 0; m < 4; ++m) MFMA(acc[m], ah[m][kk], b_h);                \
    }                                                                          \
    _Pragma("unroll")                                                          \
    for (int m = 0; m < 4; ++m)                                                \
      _Pragma("unroll")                                                        \
      for (int j = 0; j < 4; ++j)                                              \
        qf[m][OH][j] = fmaf(hc[m * 4 + j], acc[m][j] + (WB), qf[m][OH][j]);    \
  }

  for (int t2 = 0; t2 < 128; ++t2) {
    const int ct0 = t2 * 2;
    // h column t2 for this wave's 64 rows (16 values/lane across kg groups)
    float hc[16];
    {
      const float* hp = Hh + (size_t)(wrow + kg * 4) * 128 + t2;
#pragma unroll
      for (int m = 0; m < 4; ++m)
#pragma unroll
        for (int j = 0; j < 4; ++j)
          hc[m * 4 + j] = hp[(size_t)(m * 16 + j) * 128];
    }
    float wb0 = hwb[ct0 * 16 + cl];
    float wb1 = hwb[(ct0 + 1) * 16 + cl];
    // issue loads for chunk ct0+1
    short8_t s1a = *(const short8_t*)(Wp + (size_t)(ct0 + 1) * 4096 + tid * 16);
    short8_t s1b = *(const short8_t*)(Wp + (size_t)(ct0 + 1) * 4096 + tid * 16 + 8);
    COMPUTE_HALF(0, 0, wb0)
    *(short8_t*)&Bh[1][tid * 16] = s1a;
    *(short8_t*)&Bh[1][tid * 16 + 8] = s1b;
    __syncthreads();
    short8_t s2a, s2b;
    if (t2 < 127) {
      s2a = *(const short8_t*)(Wp + (size_t)(ct0 + 2) * 4096 + tid * 16);
      s2b = *(const short8_t*)(Wp + (size_t)(ct0 + 2) * 4096 + tid * 16 + 8);
    }
    COMPUTE_HALF(1, 1, wb1)
    if (t2 < 127) {
      *(short8_t*)&Bh[0][tid * 16] = s2a;
      *(short8_t*)&Bh[0][tid * 16 + 8] = s2b;
    }
    __syncthreads();
  }
#undef COMPUTE_HALF

  // ---- fc2_b part: gs @ hb_w via packed chunks 256/257 (read direct from L2) ----
#pragma unroll
  for (int oh = 0; oh < 2; ++oh) {
    f32x4_t bacc[4];
#pragma unroll
    for (int m = 0; m < 4; ++m) bacc[m] = (f32x4_t){0.f, 0.f, 0.f, 0.f};
#pragma unroll
    for (int kk = 0; kk < 8; ++kk) {
      short8_t b_h = *(const short8_t*)(Wp + (((size_t)(256 + oh) * 8 + kk) * 64 + lane) * 8);
#pragma unroll
      for (int m = 0; m < 4; ++m) MFMA(bacc[m], ah[m][kk], b_h);
    }
#pragma unroll
    for (int m = 0; m < 4; ++m)
#pragma unroll
      for (int j = 0; j < 4; ++j) qf[m][oh][j] += bacc[m][j];
  }

  // ---- epilogue: q = qf + hb_b (rows disjoint per wave) ----
  float hbb0 = hbb[cl], hbb1 = hbb[16 + cl];
#pragma unroll
  for (int m = 0; m < 4; ++m)
#pragma unroll
    for (int j = 0; j < 4; ++j) {
      const size_t r = (size_t)(wrow + m * 16 + kg * 4 + j) * 32;
      Qout[r + cl] = qf[m][0][j] + hbb0;
      Qout[r + 16 + cl] = qf[m][1][j] + hbb1;
    }
}

extern "C" void kernel_launch(void* const* d_in, const int* in_sizes, int n_in,
                              void* d_out, int out_size, void* d_ws, size_t ws_size,
                              hipStream_t stream) {
  const float* inputs   = (const float*)d_in[0];
  const float* hidden   = (const float*)d_in[1];
  const float* fc1_w    = (const float*)d_in[2];
  const float* fc1_b    = (const float*)d_in[3];
  const float* gru_wi   = (const float*)d_in[4];
  const float* gru_wh   = (const float*)d_in[5];
  const float* gru_bi   = (const float*)d_in[6];
  const float* gru_bh   = (const float*)d_in[7];
  const float* attn_q_w = (const float*)d_in[8];
  const float* attn_k_w = (const float*)d_in[9];
  const float* se1_w    = (const float*)d_in[10];
  const float* se1_b    = (const float*)d_in[11];
  const float* se2_w    = (const float*)d_in[12];
  const float* se2_b    = (const float*)d_in[13];
  const float* ga_w     = (const float*)d_in[14];
  const float* ga_b     = (const float*)d_in[15];
  const float* gemb     = (const float*)d_in[16];
  const float* gd1_w    = (const float*)d_in[17];
  const float* gd1_b    = (const float*)d_in[18];
  const float* gd2_w    = (const float*)d_in[19];
  const float* gd2_b    = (const float*)d_in[20];
  const float* hb_w     = (const float*)d_in[21];
  const float* hb_b     = (const float*)d_in[22];
  const float* hw_w     = (const float*)d_in[23];
  const float* hw_b     = (const float*)d_in[24];

  float* out = (float*)d_out;
  float* q_out     = out;              // [R,32]
  float* h_out     = out + 2097152;    // [R,128]
  float* gs_out    = out + 10485760;   // [R,256]
  float* probs_out = out + 27262976;   // [R,3]
  float* attn_out  = out + 27459584;   // [B,32,32]

  // workspace layout:
  //   region0 [0, 64MiB):  qk [R,256] -> s1 [R,256] -> t [R,256] (gd1 in-place)
  //   si      [64, 80MiB): [R,64] padded struct_input
  //   x1      [80, 112MiB): [R,128]
  //   packs   [112MiB, +2.9MiB)
  float* ws = (float*)d_ws;
  float* qk = ws;
  float* s1 = ws;
  float* t  = ws;
  float* si = ws + 16777216;
  float* x1 = ws + 16777216 + 4194304;
  short* P  = (short*)((char*)d_ws + (size_t)112 * 1024 * 1024);

  // pack offsets (shorts); chunk = KK*512 shorts
  const size_t o_hw  = 0;        // K=256 KK=8, N=4096 -> 1,048,576
  const size_t o_hb  = 1048576;  // K=256 KK=8, N=32   -> 8,192 (chunks 256..257 of hw base)
  const size_t o_fc1 = 1056768;  // K=160 KK=5, N=128  -> 20,480
  const size_t o_wi  = 1077248;  // K=128 KK=4, N=384  -> 49,152
  const size_t o_wh  = 1126400;  // 49,152
  const size_t o_qkq = 1175552;  // K=128 KK=4, N=128  -> 16,384
  const size_t o_qkk = 1191936;  // 16,384 (contiguous after q: chunks 8..15)
  const size_t o_se1 = 1208320;  // K=34->64 KK=2, N=256 -> 16,384
  const size_t o_se2 = 1224704;  // K=256 KK=8, N=256  -> 65,536
  const size_t o_gd1 = 1290240;  // 65,536
  const size_t o_gd2 = 1355776;  // 65,536

  PackArgs pa;
  pa.s[0]  = {hw_w,     256, 4096, 8, 0,    4096, o_hw};
  pa.s[1]  = {hb_w,     256, 32,   8, 4096, 32,   o_hb};
  pa.s[2]  = {fc1_w,    160, 128,  5, 4128, 80,   o_fc1};
  pa.s[3]  = {gru_wi,   128, 384,  4, 4208, 192,  o_wi};
  pa.s[4]  = {gru_wh,   128, 384,  4, 4400, 192,  o_wh};
  pa.s[5]  = {attn_q_w, 128, 128,  4, 4592, 64,   o_qkq};
  pa.s[6]  = {attn_k_w, 128, 128,  4, 4656, 64,   o_qkk};
  pa.s[7]  = {se1_w,    34,  256,  2, 4720, 64,   o_se1};
  pa.s[8]  = {se2_w,    256, 256,  8, 4784, 256,  o_se2};
  pa.s[9]  = {gd1_w,    256, 256,  8, 5040, 256,  o_gd1};
  pa.s[10] = {gd2_w,    256, 256,  8, 5296, 256,  o_gd2};

  dim3 blk(256);
  // 0) pack ALL weights in one launch (5552 blocks)
  pack_all_kernel<<<5552, blk, 0, stream>>>(pa, P);
  // 1) x1 = relu(inputs @ fc1_w + fc1_b)            K=160 N=128
  mfma_gemm_kernel<5, 8, 1><<<512, blk, 0, stream>>>(inputs, 160, P + o_fc1, fc1_b, x1);
  // 2) h = GRUCell(x1, hidden)
  gru_mfma_kernel<<<512, blk, 0, stream>>>(x1, hidden, P + o_wi, P + o_wh, gru_bi, gru_bh, h_out);
  // 3) qk = h @ [attn_q_w | attn_k_w]               K=128 N=256
  mfma_gemm_kernel<4, 16, 0><<<512, blk, 0, stream>>>(h_out, 128, P + o_qkq, nullptr, qk);
  // 4) attention -> attn_out + padded struct_input
  attn_kernel<<<2048, blk, 0, stream>>>(qk, attn_out, si);
  // 5) s1 = relu(si @ se1_w + se1_b)                K=64(pad) N=256
  mfma_gemm_kernel<2, 16, 1><<<512, blk, 0, stream>>>(si, 64, P + o_se1, se1_b, s1);
  // 6) struct_feat = tanh(s1 @ se2_w + se2_b) -> staged in gs_out
  mfma_gemm_kernel<8, 16, 2><<<512, blk, 0, stream>>>(s1, 256, P + o_se2, se2_b, gs_out);
  // 7) probs + t = sf + probs@group_emb
  group_kernel<<<16384, blk, 0, stream>>>(gs_out, ga_w, ga_b, gemb, probs_out, t);
  // 8) g1 = relu(t @ gd1_w + gd1_b)  (in-place)
  mfma_gemm_kernel<8, 16, 1><<<512, blk, 0, stream>>>(t, 256, P + o_gd1, gd1_b, t);
  // 9) group_state = tanh(g1 @ gd2_w + gd2_b) -> gs_out
  mfma_gemm_kernel<8, 16, 2><<<512, blk, 0, stream>>>(t, 256, P + o_gd2, gd2_b, gs_out);
  // 10) q: pure-bf16 MFMA hypernet, biases folded
  hyper_q_hi_kernel<<<dim3(256), blk, 0, stream>>>(gs_out, h_out, P + o_hw, hw_b, hb_b, q_out);
}